// Round 7
// baseline (271.233 us; speedup 1.0000x reference)
//
#include <hip/hip_runtime.h>
#include <math.h>

#define BB   4
#define NN   8192
#define BN   (BB*NN)       // 32768 points per cloud-set; 8 clouds of 8192 total
#define KNN  10
#define G    32            // grid cells per dim
#define NCELLS (G*G*G)     // 32768 cells per cloud
#define GRID_LO (-5.0f)
#define H    0.3125f       // 10/32
#define INV_H 3.2f
#define RCAP 2             // rho<=2 region; beyond -> brute overflow

#define SEPS    5.9604645e-8f        // slamch('E') = 2^-24
#define SEPS2   (SEPS*SEPS)
#define SSAFMIN 1.1754944e-38f

__device__ __forceinline__ int cellc(float v) {
    int c = (int)floorf((v - GRID_LO) * INV_H);
    return min(G - 1, max(0, c));
}

// ---------------------------------------------------------------------------
// Kernel A: build P4[8][8192] = (x,y,z, bitcast orig-idx); clouds 0-3 = gt
// batches, 4-7 = pred[idx12] batches. Histogram cells + zero accumulators.
// ---------------------------------------------------------------------------
__global__ __launch_bounds__(256) void prep_kernel(
    const float* __restrict__ gt, const float* __restrict__ pred,
    const unsigned* __restrict__ idxw, float4* __restrict__ P4,
    int* __restrict__ hist, float* __restrict__ accum,
    unsigned* __restrict__ counter, int* __restrict__ ovf_count)
{
    __shared__ int s_is32;
    int tid = threadIdx.x;
    if (tid == 0) s_is32 = 0;
    __syncthreads();
    if (idxw[2*tid + 1] != 0u) s_is32 = 1;   // int64 => all high words 0
    __syncthreads();
    bool is64 = (s_is32 == 0);

    if (blockIdx.x == 0 && tid == 0) {
        *accum = 0.0f; *counter = 0u; *ovf_count = 0;
    }

    int point = blockIdx.x * 256 + tid;        // 0 .. 2*BN-1
    int pair = point >> 13;                    // 0..7
    int r    = point & (NN - 1);               // idx within cloud
    float x, y, z;
    if (point < BN) {
        const float* s = gt + (size_t)point*3;
        x = s[0]; y = s[1]; z = s[2];
    } else {
        int rr = point - BN;
        int b = rr >> 13;
        unsigned idx = is64 ? idxw[2*(size_t)rr] : idxw[rr];
        const float* s = pred + ((size_t)b*NN + idx)*3;
        x = s[0]; y = s[1]; z = s[2];
    }
    P4[point] = make_float4(x, y, z, __int_as_float(r));
    int cell = (cellc(z)*G + cellc(y))*G + cellc(x);
    atomicAdd(&hist[(size_t)pair*NCELLS + cell], 1);
}

// ---------------------------------------------------------------------------
// Kernel B: per-cloud exclusive scan -> combo[c] = int2(start, count).
// ---------------------------------------------------------------------------
__global__ __launch_bounds__(1024) void scan_kernel(
    const int* __restrict__ hist, int2* __restrict__ combo)
{
    int cloud = blockIdx.x;
    int tid = threadIdx.x;
    int lane = tid & 63, wid = tid >> 6;
    const int* h = hist + (size_t)cloud * NCELLS;
    int2* cb = combo + (size_t)cloud * NCELLS;

    int loc[32];
    int base = tid * 32;
    const int4* h4 = (const int4*)(h + base);
    int sum = 0;
    #pragma unroll
    for (int i = 0; i < 8; ++i) {
        int4 a = h4[i];
        loc[4*i+0] = a.x; loc[4*i+1] = a.y; loc[4*i+2] = a.z; loc[4*i+3] = a.w;
        sum += a.x + a.y + a.z + a.w;
    }
    // inclusive wave scan of sums
    int v = sum;
    #pragma unroll
    for (int off = 1; off < 64; off <<= 1) {
        int o = __shfl_up(v, off, 64);
        if (lane >= off) v += o;
    }
    __shared__ int ws[16], wsx[16];
    if (lane == 63) ws[wid] = v;
    __syncthreads();
    if (tid < 16) {
        int acc = 0;
        for (int i = 0; i < tid; ++i) acc += ws[i];
        wsx[tid] = acc;
    }
    __syncthreads();
    int run = (v - sum) + wsx[wid];            // exclusive prefix for this thread

    int4* cb4 = (int4*)(cb + base);            // 2 cells per int4 store
    #pragma unroll
    for (int i = 0; i < 16; ++i) {
        int4 o;
        o.x = run; o.y = loc[2*i];     run += loc[2*i];
        o.z = run; o.w = loc[2*i+1];   run += loc[2*i+1];
        cb4[i] = o;
    }
}

// ---------------------------------------------------------------------------
// Kernel C: scatter points into cell-sorted S.
// ---------------------------------------------------------------------------
__global__ __launch_bounds__(256) void scatter_kernel(
    const float4* __restrict__ P4, int* __restrict__ hist,
    const int2* __restrict__ combo, float4* __restrict__ S)
{
    int point = blockIdx.x * 256 + threadIdx.x;
    float4 p = P4[point];
    int pair = point >> 13;
    int cell = (cellc(p.z)*G + cellc(p.y))*G + cellc(p.x);
    int old = atomicSub(&hist[(size_t)pair*NCELLS + cell], 1);
    int pos = combo[(size_t)pair*NCELLS + cell].x + old - 1;
    S[(size_t)pair*NN + pos] = p;
}

// ---------------------------------------------------------------------------
// LAPACK ssyevd 3x3 path: ssytrd('L') + sorgtr + ssteqr('V'). Sign-faithful.
// (verified absmax 0.0 in rounds 2-18 — do not touch)
// ---------------------------------------------------------------------------
__device__ __forceinline__ float f_sign(float a, float b) {
    return copysignf(a, b);
}
__device__ __forceinline__ float slapy2(float x, float y) {
#pragma clang fp contract(off)
    float xa = fabsf(x), ya = fabsf(y);
    float w = fmaxf(xa, ya), z = fminf(xa, ya);
    if (z == 0.0f) return w;
    float t = z / w;
    return w * __fsqrt_rn(1.0f + t*t);
}
__device__ __forceinline__ void slartg_(float f, float g, float* cs, float* sn, float* r) {
#pragma clang fp contract(off)
    if (g == 0.0f)      { *cs = 1.0f; *sn = 0.0f; *r = f; }
    else if (f == 0.0f) { *cs = 0.0f; *sn = f_sign(1.0f, g); *r = fabsf(g); }
    else {
        float f1 = fabsf(f);
        float d = __fsqrt_rn(f*f + g*g);
        float p = 1.0f / d;
        *cs = f1 * p;
        *sn = g * f_sign(p, f);
        *r  = f_sign(d, f);
    }
}
__device__ void slaev2_(float a, float b, float c,
                        float* rt1, float* rt2, float* cs1, float* sn1) {
#pragma clang fp contract(off)
    float sm = a + c, df = a - c;
    float adf = fabsf(df);
    float tb = b + b;
    float ab = fabsf(tb);
    float acmx, acmn;
    if (fabsf(a) > fabsf(c)) { acmx = a; acmn = c; } else { acmx = c; acmn = a; }
    float rt;
    if (adf > ab)      { float t = ab/adf; rt = adf*__fsqrt_rn(1.0f + t*t); }
    else if (adf < ab) { float t = adf/ab; rt = ab*__fsqrt_rn(1.0f + t*t); }
    else               { rt = ab*__fsqrt_rn(2.0f); }
    int sgn1;
    if (sm < 0.0f)      { *rt1 = 0.5f*(sm - rt); sgn1 = -1;
                          *rt2 = (acmx / *rt1)*acmn - (b / *rt1)*b; }
    else if (sm > 0.0f) { *rt1 = 0.5f*(sm + rt); sgn1 = 1;
                          *rt2 = (acmx / *rt1)*acmn - (b / *rt1)*b; }
    else                { *rt1 = 0.5f*rt; *rt2 = -0.5f*rt; sgn1 = 1; }
    float cs; int sgn2;
    if (df >= 0.0f) { cs = df + rt; sgn2 = 1; } else { cs = df - rt; sgn2 = -1; }
    float acs = fabsf(cs);
    float c1, s1;
    if (acs > ab) { float ct = -tb/cs; s1 = 1.0f/__fsqrt_rn(1.0f + ct*ct); c1 = ct*s1; }
    else {
        if (ab == 0.0f) { c1 = 1.0f; s1 = 0.0f; }
        else { float tn = -cs/tb; c1 = 1.0f/__fsqrt_rn(1.0f + tn*tn); s1 = tn*c1; }
    }
    if (sgn1 == sgn2) { float tn = c1; c1 = -s1; s1 = tn; }
    *cs1 = c1; *sn1 = s1;
}

__device__ void eigh3_smallest(float c00, float c01, float c02,
                               float c11, float c12, float c22, float nv[3])
{
#pragma clang fp contract(off)
    // ---- ssytrd('L') ----
    float d[4], e[3], z[4][4];
    float tau1, v2 = 0.0f;
    float e1, d2, d3, e2;
    float alpha = c01, x = c02;
    if (x == 0.0f) {
        tau1 = 0.0f; e1 = alpha;
        d2 = c11; d3 = c22; e2 = c12;
    } else {
        float beta = -f_sign(slapy2(alpha, fabsf(x)), alpha);
        tau1 = (beta - alpha) / beta;
        v2 = x / (alpha - beta);
        e1 = beta;
        float w1 = tau1*(c11 + c12*v2);
        float w2 = tau1*(c12 + c22*v2);
        float al = -0.5f*tau1*(w1 + w2*v2);
        w1 = w1 + al;
        w2 = w2 + al*v2;
        d2 = (c11 - w1) - w1;
        e2 = (c12 - v2*w1) - w2;
        d3 = (c22 - v2*w2) - w2*v2;
    }
    d[1] = c00; d[2] = d2; d[3] = d3;
    e[1] = e1;  e[2] = e2;
    z[1][1] = 1.0f; z[1][2] = 0.0f; z[1][3] = 0.0f;
    z[2][1] = 0.0f; z[3][1] = 0.0f;
    z[2][2] = 1.0f - tau1;
    float mtv = -tau1*v2;
    z[2][3] = mtv; z[3][2] = mtv;
    z[3][3] = 1.0f + mtv*v2;

    // ---- ssteqr('V', 3) ----
    const int n = 3, nm1 = 2;
    int l1 = 1, jtot = 0;
    const int nmaxit = 90;
    float cw[3], sw[3];
    int guard = 0;
    while (guard++ < 64) {
        if (l1 > n) break;
        if (l1 > 1) e[l1-1] = 0.0f;
        int m = n;
        if (l1 <= nm1) {
            for (int mi = l1; mi <= nm1; ++mi) {
                float tst = fabsf(e[mi]);
                if (tst == 0.0f) { m = mi; break; }
                if (tst <= (__fsqrt_rn(fabsf(d[mi]))*__fsqrt_rn(fabsf(d[mi+1])))*SEPS) {
                    e[mi] = 0.0f; m = mi; break;
                }
            }
        }
        int l = l1;
        int lsv = l, lend = m, lendsv = lend;
        l1 = m + 1;
        if (lend == l) continue;
        if (fabsf(d[lend]) < fabsf(d[l])) { lend = lsv; l = lendsv; }

        if (lend > l) {
            // QL
            while (true) {
                int m_ = lend;
                if (l != lend) {
                    for (int mi = l; mi <= lend-1; ++mi) {
                        float em = e[mi];
                        float tst = em*em;
                        if (tst <= (SEPS2*fabsf(d[mi]))*fabsf(d[mi+1]) + SSAFMIN) { m_ = mi; break; }
                    }
                }
                if (m_ < lend) e[m_] = 0.0f;
                float p = d[l];
                if (m_ == l) {
                    d[l] = p; l = l + 1;
                    if (l <= lend) continue; else break;
                }
                if (m_ == l + 1) {
                    float rt1, rt2, cc, ss;
                    slaev2_(d[l], e[l], d[l+1], &rt1, &rt2, &cc, &ss);
                    for (int i = 1; i <= 3; ++i) {
                        float tmp = z[i][l+1];
                        z[i][l+1] = cc*tmp - ss*z[i][l];
                        z[i][l]   = ss*tmp + cc*z[i][l];
                    }
                    d[l] = rt1; d[l+1] = rt2; e[l] = 0.0f;
                    l = l + 2;
                    if (l <= lend) continue; else break;
                }
                if (jtot == nmaxit) break;
                jtot++;
                float g = (d[l+1] - p) / (2.0f*e[l]);
                float r = slapy2(g, 1.0f);
                g = d[m_] - p + (e[l] / (g + f_sign(r, g)));
                float s = 1.0f, c = 1.0f;
                p = 0.0f;
                for (int i = m_-1; i >= l; --i) {
                    float f = s*e[i];
                    float b = c*e[i];
                    slartg_(g, f, &c, &s, &r);
                    if (i != m_-1) e[i+1] = r;
                    g = d[i+1] - p;
                    r = (d[i] - g)*s + (2.0f*c)*b;
                    p = s*r;
                    d[i+1] = g + p;
                    g = c*r - b;
                    cw[i] = c; sw[i] = -s;
                }
                for (int j = m_-1; j >= l; --j) {
                    float cc = cw[j], ss = sw[j];
                    for (int i = 1; i <= 3; ++i) {
                        float tmp = z[i][j+1];
                        z[i][j+1] = cc*tmp - ss*z[i][j];
                        z[i][j]   = ss*tmp + cc*z[i][j];
                    }
                }
                d[l] = d[l] - p;
                e[l] = g;
            }
        } else {
            // QR
            while (true) {
                int m_ = lend;
                if (l != lend) {
                    for (int mi = l; mi >= lend+1; --mi) {
                        float em = e[mi-1];
                        float tst = em*em;
                        if (tst <= (SEPS2*fabsf(d[mi]))*fabsf(d[mi-1]) + SSAFMIN) { m_ = mi; break; }
                    }
                }
                if (m_ > lend) e[m_-1] = 0.0f;
                float p = d[l];
                if (m_ == l) {
                    d[l] = p; l = l - 1;
                    if (l >= lend) continue; else break;
                }
                if (m_ == l - 1) {
                    float rt1, rt2, cc, ss;
                    slaev2_(d[l-1], e[l-1], d[l], &rt1, &rt2, &cc, &ss);
                    for (int i = 1; i <= 3; ++i) {
                        float tmp = z[i][l];
                        z[i][l]   = cc*tmp - ss*z[i][l-1];
                        z[i][l-1] = ss*tmp + cc*z[i][l-1];
                    }
                    d[l-1] = rt1; d[l] = rt2; e[l-1] = 0.0f;
                    l = l - 2;
                    if (l >= lend) continue; else break;
                }
                if (jtot == nmaxit) break;
                jtot++;
                float g = (d[l-1] - p) / (2.0f*e[l-1]);
                float r = slapy2(g, 1.0f);
                g = d[m_] - p + (e[l-1] / (g + f_sign(r, g)));
                float s = 1.0f, c = 1.0f;
                p = 0.0f;
                for (int i = m_; i <= l-1; ++i) {
                    float f = s*e[i];
                    float b = c*e[i];
                    slartg_(g, f, &c, &s, &r);
                    if (i != m_) e[i-1] = r;
                    g = d[i] - p;
                    r = (d[i+1] - g)*s + (2.0f*c)*b;
                    p = s*r;
                    d[i] = g + p;
                    g = c*r - b;
                    cw[i] = c; sw[i] = s;
                }
                for (int j = m_; j <= l-1; ++j) {
                    float cc = cw[j], ss = sw[j];
                    for (int i = 1; i <= 3; ++i) {
                        float tmp = z[i][j+1];
                        z[i][j+1] = cc*tmp - ss*z[i][j];
                        z[i][j]   = ss*tmp + cc*z[i][j];
                    }
                }
                d[l] = d[l] - p;
                e[l-1] = g;
            }
        }
    }
    for (int ii = 2; ii <= 3; ++ii) {
        int i = ii - 1, k = i;
        float p = d[i];
        for (int j = ii; j <= 3; ++j) if (d[j] < p) { k = j; p = d[j]; }
        if (k != i) {
            d[k] = d[i]; d[i] = p;
            for (int r2 = 1; r2 <= 3; ++r2) {
                float t = z[r2][i]; z[r2][i] = z[r2][k]; z[r2][k] = t;
            }
        }
    }
    nv[0] = z[1][1]; nv[1] = z[2][1]; nv[2] = z[3][1];
}

// Covariance of the sorted 10-neighborhood (same op order as rounds 2-18).
__device__ void cov_compute(const float4* __restrict__ cl,
                            const unsigned long long keys[KNN], float c[6])
{
#pragma clang fp contract(off)
    float px[KNN], py[KNN], pz[KNN];
    float sx = 0.f, sy = 0.f, sz = 0.f;
    #pragma unroll
    for (int s = 0; s < KNN; ++s) {
        int ni = (int)(unsigned)(keys[s] & 0xFFFFFFFFull);
        float4 np = cl[ni];
        px[s] = np.x; py[s] = np.y; pz[s] = np.z;
        sx = sx + px[s]; sy = sy + py[s]; sz = sz + pz[s];
    }
    float mx = sx / 10.0f, my = sy / 10.0f, mz = sz / 10.0f;
    float c00=0.f,c01=0.f,c02=0.f,c11=0.f,c12=0.f,c22=0.f;
    #pragma unroll
    for (int s = 0; s < KNN; ++s) {
        float dx = px[s]-mx, dy = py[s]-my, dz = pz[s]-mz;
        c00 = c00 + dx*dx; c01 = c01 + dx*dy; c02 = c02 + dx*dz;
        c11 = c11 + dy*dy; c12 = c12 + dy*dz; c22 = c22 + dz*dz;
    }
    c[0] = c00/10.0f; c[1] = c01/10.0f; c[2] = c02/10.0f;
    c[3] = c11/10.0f; c[4] = c12/10.0f; c[5] = c22/10.0f;
}

// ---------------------------------------------------------------------------
// Insert: gate = min(own 10th, quad bound). Dropping candidates >= the quad
// bound is exact: some lane already holds 10 strictly-better keys. In phase 2
// qbK is ~0ull so the gate degenerates to the (exact) own 10th.
// ---------------------------------------------------------------------------
#define PROC(p) do { \
    float ddx = qx - (p).x, ddy = qy - (p).y, ddz = qz - (p).z; \
    float dd = fmaf(ddz, ddz, fmaf(ddy, ddy, ddx*ddx)); \
    unsigned long long key = \
        ((unsigned long long)__float_as_uint(dd) << 32) | \
        (unsigned)__float_as_int((p).w); \
    if (key < kgate) { \
        unsigned long long ck = key; \
        _Pragma("unroll") \
        for (int s = 0; s < KNN; ++s) { \
            unsigned long long ok2 = keys[s]; \
            bool sw = ok2 > ck; \
            keys[s] = sw ? ck : ok2; \
            ck      = sw ? ok2 : ck; \
        } \
        k9 = keys[KNN-1]; \
        kgate = (k9 < qbK) ? k9 : qbK; \
    } \
} while (0)

// R24 cooperative stride-4 segment walk: the QUAD jointly covers [bgn,end);
// lane sub takes elements bgn+sub, +4, +8, ... Perfect quad balance (steps =
// ceil(len/4), no per-lane row raggedness) and the quad's 4 loads are one
// contiguous 64B chunk (4x fewer cache lines per step than per-lane rows).
// Disjointness across lanes preserved -> per-lane exact reservoirs.
#define SEGPROC(bgn, end) do { \
    int _j = (bgn) + sub, _je = (end); \
    for (; _j + 4 < _je; _j += 8) { \
        float4 _p0 = cs[_j]; float4 _p1 = cs[_j+4]; \
        PROC(_p0); PROC(_p1); \
    } \
    if (_j < _je) { float4 _p0 = cs[_j]; PROC(_p0); } \
} while (0)

// quad-min of the four lanes' current 10th keys; low word forced to all-ones
// so ties on the distance bits still pass the gate (tie-exact).
#define QEXCH() do { \
    unsigned long long _o1 = __shfl_xor(k9, 1, 4); \
    unsigned long long _m1 = (_o1 < k9) ? _o1 : k9; \
    unsigned long long _o2 = __shfl_xor(_m1, 2, 4); \
    unsigned long long _qm = (_o2 < _m1) ? _o2 : _m1; \
    qbK = _qm | 0xFFFFFFFFull; \
    kgate = (k9 < qbK) ? k9 : qbK; \
} while (0)

// R24 quad EXTRACTION merge: 10 rounds; per round a 2-stage u64-min butterfly
// finds the global min of the 4 sorted lists, every lane records it, every
// lane whose head equals it shifts down (shared keys collapse -> natural
// dedupe). Exact top-10 of the union, ascending, IDENTICAL in all 4 lanes.
#define QMERGE() do { \
    unsigned long long fin[KNN]; \
    _Pragma("unroll") \
    for (int r = 0; r < KNN; ++r) { \
        unsigned long long m = keys[0]; \
        unsigned long long _o1 = __shfl_xor(m, 1, 4); m = (_o1 < m) ? _o1 : m; \
        unsigned long long _o2 = __shfl_xor(m, 2, 4); m = (_o2 < m) ? _o2 : m; \
        fin[r] = m; \
        bool own = (keys[0] == m); \
        _Pragma("unroll") \
        for (int t = 0; t < KNN-1; ++t) keys[t] = own ? keys[t+1] : keys[t]; \
        keys[KNN-1] = own ? 0xFFFFFFFFFFFFFFFFull : keys[KNN-1]; \
    } \
    _Pragma("unroll") \
    for (int s = 0; s < KNN; ++s) keys[s] = fin[s]; \
    k9 = keys[KNN-1]; \
} while (0)

// ---------------------------------------------------------------------------
// Kernel D (R26): R24/R25 algorithm unchanged; blocks shrunk 256 -> 64
// threads (4096 blocks). Each wave still covers 16 CONSECUTIVE qids (identical
// per-wave cost structure), but scheduling granularity is now per-wave, not
// per-4-wave-block (block duration was max of 4 waves; stragglers pinned CUs).
// Swizzle: b -> (i=b&255 [CU under round-robin], j=b>>8) ->
// bb = ((i>>5)<<9)|(j<<5)|(i&31): each CU's 16 blocks land in ONE cloud
// (L2-friendly) at z-positions spread stride-32-blocks (=512 queries) across
// the cloud's density range. Bijective; pure scheduling permutation ->
// bit-identical output.
// ---------------------------------------------------------------------------
__global__ __launch_bounds__(64) void knn_main_kernel(
    const float4* __restrict__ P4, const float4* __restrict__ S,
    const int2* __restrict__ combo, float4* __restrict__ Cov,
    int* __restrict__ ovf, unsigned long long* __restrict__ ovf_key,
    int* __restrict__ ovf_count)
{
    int b = blockIdx.x;                         // 0..4095
    int bb = (((b & 255) >> 5) << 9) | ((b >> 8) << 5) | (b & 31);
    int tidg = bb * 64 + threadIdx.x;           // 0..262143
    int qid  = tidg >> 2;                       // 0..65535
    int sub  = tidg & 3;
    int pair = qid >> 13;                       // 8 clouds
    int spos = qid & (NN - 1);                  // sorted position
    const float4* __restrict__ cl = P4 + (size_t)pair * NN;
    const float4* __restrict__ cs = S  + (size_t)pair * NN;
    const int2*   __restrict__ cb = combo + (size_t)pair * NCELLS;

    float4 q = cs[spos];
    float qx = q.x, qy = q.y, qz = q.z;
    int qi = __float_as_int(q.w);               // original index in cloud
    int qcx = cellc(qx), qcy = cellc(qy), qcz = cellc(qz);

    unsigned long long keys[KNN];
    #pragma unroll
    for (int s = 0; s < KNN; ++s) keys[s] = 0xFFFFFFFFFFFFFFFFull;
    unsigned long long k9    = 0xFFFFFFFFFFFFFFFFull;
    unsigned long long qbK   = 0xFFFFFFFFFFFFFFFFull;
    unsigned long long kgate = 0xFFFFFFFFFFFFFFFFull;

    // ---- phase 1: rho<=1 cube = 9 (z,y) rows, center-out order so gates
    // tighten early; QEXCH between rows shares the quad bound.
    int x0 = max(qcx - 1, 0), x1 = min(qcx + 1, G - 1);
    {
        const int DZ9[9] = { 0,  0,  0, -1,  1, -1, -1,  1,  1};
        const int DY9[9] = { 0,  1, -1,  0,  0, -1,  1, -1,  1};
        int rb[9], re[9];
        #pragma unroll
        for (int r = 0; r < 9; ++r) {
            int zz = qcz + DZ9[r], yy = qcy + DY9[r];
            rb[r] = 0; re[r] = 0;
            if ((unsigned)zz < G && (unsigned)yy < G) {
                int cbase = (zz*G + yy)*G;
                int2 a  = cb[cbase + x0];
                int2 b2 = cb[cbase + x1];
                rb[r] = a.x; re[r] = b2.x + b2.y;
            }
        }
        #pragma unroll
        for (int r = 0; r < 9; ++r) {
            SEGPROC(rb[r], re[r]);
            if (r == 0 || r == 2 || r == 4 || r == 6) QEXCH();
        }
    }

    // ---- quad extraction-merge -> exact cube top-10, identical in all lanes
    QMERGE();
    const unsigned long long k9M = k9;          // exact cube 10th (u64 key)
    float worstM = __uint_as_float((unsigned)(k9M >> 32)); // NaN if <10 found

    // ---- phase 2: rho=2 shell. Exterior of the cube is >= H from q, so
    // skip iff H^2 > worstM is EXACT (NaN-safe: NaN -> walk shell).
    bool skip = (H*H > worstM);                 // quad-uniform (worstM shared)

    qbK   = 0xFFFFFFFFFFFFFFFFull;              // phase-2 gate = own 10th
    kgate = k9;
    if (!skip) {
        int xs0 = max(qcx - 2, 0), xs1 = min(qcx + 2, G - 1);
        // 16 outer rows; box test redundant in all 4 lanes (same q -> same
        // result, quad-uniform branch), then cooperative stride-4 walk.
        const int SZ16[16] = {-2,-2,-2,-2,-2,  2, 2, 2, 2, 2, -1,-1, 0, 0, 1, 1};
        const int SY16[16] = {-2,-1, 0, 1, 2, -2,-1, 0, 1, 2, -2, 2,-2, 2,-2, 2};
        #pragma unroll
        for (int r = 0; r < 16; ++r) {
            int zz = qcz + SZ16[r], yy = qcy + SY16[r];
            if ((unsigned)zz < G && (unsigned)yy < G) {
                float loy = fmaf((float)yy, H, GRID_LO);
                float loz = fmaf((float)zz, H, GRID_LO);
                float py = fmaxf(0.0f, fmaxf(loy - qy, qy - (loy + H)));
                float pz = fmaxf(0.0f, fmaxf(loz - qz, qz - (loz + H)));
                float pyz = fmaf(pz, pz, py*py);
                if (!(pyz > worstM)) {
                    int cbase = (zz*G + yy)*G;
                    int2 a  = cb[cbase + xs0];
                    int2 b2 = cb[cbase + xs1];
                    SEGPROC(a.x, b2.x + b2.y);
                }
            }
        }
        // 18 isolated cells (|dz|<=1,|dy|<=1, dx=+/-2)
        const int CZ18[18] = {-1,-1,-1,-1,-1,-1,  0, 0, 0, 0, 0, 0,  1, 1, 1, 1, 1, 1};
        const int CY18[18] = {-1,-1, 0, 0, 1, 1, -1,-1, 0, 0, 1, 1, -1,-1, 0, 0, 1, 1};
        const int CX18[18] = {-2, 2,-2, 2,-2, 2, -2, 2,-2, 2,-2, 2, -2, 2,-2, 2,-2, 2};
        #pragma unroll
        for (int r = 0; r < 18; ++r) {
            int zz = qcz + CZ18[r], yy = qcy + CY18[r], xx = qcx + CX18[r];
            if ((unsigned)zz < G && (unsigned)yy < G && (unsigned)xx < G) {
                float lox = fmaf((float)xx, H, GRID_LO);
                float loy = fmaf((float)yy, H, GRID_LO);
                float loz = fmaf((float)zz, H, GRID_LO);
                float px = fmaxf(0.0f, fmaxf(lox - qx, qx - (lox + H)));
                float py = fmaxf(0.0f, fmaxf(loy - qy, qy - (loy + H)));
                float pz = fmaxf(0.0f, fmaxf(loz - qz, qz - (loz + H)));
                float m2 = fmaf(pz, pz, fmaf(py, py, px*px));
                if (!(m2 > worstM)) {
                    int2 a = cb[(zz*G + yy)*G + xx];
                    SEGPROC(a.x, a.x + a.y);
                }
            }
        }
    }

    // ---- final: extraction-merge again, but only if some lane inserted a
    // shell candidate (every successful insert strictly lowers k9). Shared
    // cube survivors are held by all 4 lanes -> all owners shift in the same
    // round -> natural exact dedupe. skip and ch are quad-uniform.
    if (!skip) {
        int ch = (k9 != k9M) ? 1 : 0;
        ch |= __shfl_xor(ch, 1, 4);
        ch |= __shfl_xor(ch, 2, 4);
        if (ch) QMERGE();
    }
    float worst_m = __uint_as_float((unsigned)(k9 >> 32));

    // resolved iff cells beyond the rho<=2 region (gap >= 2H) cannot contribute
    float bf = (float)RCAP * H;
    bool resolved = (bf*bf > worst_m);          // strict; NaN (unfilled) -> false
    if (resolved && sub == 0) {
        float c[6];
        cov_compute(cl, keys, c);               // sub==0 only: 1/4 gather loads
        size_t o = ((size_t)pair*NN + qi)*2;
        Cov[o]   = make_float4(c[0], c[1], c[2], c[3]);
        Cov[o+1] = make_float4(c[4], c[5], 0.0f, 0.0f);
    } else if (!resolved && sub == 0) {
        int pos = atomicAdd(ovf_count, 1);
        ovf[pos] = (pair << 13) | qi;
        ovf_key[pos] = k9;      // exact 10th over examined set: valid upper
    }                           // bound on the true 10th key
}

// ---------------------------------------------------------------------------
// Kernel D2 (R26): brute-force overflow, ONE BLOCK per query. Two fixes:
// (1) BRUTE_BLOCKS 2048 -> 4096: ovf count ~2240 > 2048 meant 192 blocks ran
//     a SECOND query while 1856 idled -> duration ~2x one query. Now 1:1.
// (2) WAVE-shared bound (FAISS WarpSelect idiom): every scan iteration, a
//     6-step shfl butterfly computes the wave-min of the 64 lanes' own 10ths;
//     gate = min(own k9, wavemin|0xFFFFFFFF). Dropping key >= wavemin is
//     EXACT: the owning lane holds 10 keys with strictly smaller distance
//     bits (dd-ties pass the gate since idx < 2^32-1). This collapses the
//     insert-chain union frequency after the fill phase (gate ~ global
//     ~100th-NN distance instead of per-lane 10th-of-seen).
// Merge path unchanged from R25 (exact, ascending) => bit-identical cov.
// ---------------------------------------------------------------------------
#define BRUTE_BLOCKS 4096
__global__ __launch_bounds__(256) void brute_kernel(
    const float4* __restrict__ P4, const int* __restrict__ ovf,
    const unsigned long long* __restrict__ ovf_key,
    const int* __restrict__ ovf_count, float4* __restrict__ Cov)
{
    __shared__ unsigned long long wl[4][KNN];
    int tid = threadIdx.x;
    int lane = tid & 63;
    int wid = tid >> 6;
    int count = *ovf_count;

    for (int oi = blockIdx.x; oi < count; oi += BRUTE_BLOCKS) {
        int rec = ovf[oi];
        unsigned long long bound = ovf_key[oi];
        float bound_d = __uint_as_float((unsigned)(bound >> 32)); // NaN if unfilled
        int pair = rec >> 13;
        int qi = rec & (NN - 1);
        const float4* __restrict__ cl = P4 + (size_t)pair * NN;
        float4 q = cl[qi];
        float qx = q.x, qy = q.y, qz = q.z;

        unsigned long long keys[KNN];
        #pragma unroll
        for (int s = 0; s < KNN; ++s) keys[s] = 0xFFFFFFFFFFFFFFFFull;
        unsigned long long k9 = keys[KNN-1];
        unsigned long long wbound = 0xFFFFFFFFFFFFFFFFull;
        unsigned long long kgate  = 0xFFFFFFFFFFFFFFFFull;

        // per-thread scan of a disjoint 1/256 slice (32 candidates), gated by
        // bound_d AND min(own 10th, wave bound); ties pass (exact).
#define BPROC(p, jj) do { \
        float ddx = qx - (p).x, ddy = qy - (p).y, ddz = qz - (p).z; \
        float dd = fmaf(ddz, ddz, fmaf(ddy, ddy, ddx*ddx)); \
        if (!(dd > bound_d)) { \
            unsigned long long key = \
                ((unsigned long long)__float_as_uint(dd) << 32) | (unsigned)(jj); \
            if (key < kgate) { \
                unsigned long long ck = key; \
                _Pragma("unroll") \
                for (int s = 0; s < KNN; ++s) { \
                    unsigned long long ok2 = keys[s]; \
                    bool sw = ok2 > ck; \
                    keys[s] = sw ? ck : ok2; \
                    ck      = sw ? ok2 : ck; \
                } \
                k9 = keys[KNN-1]; \
                kgate = (k9 < wbound) ? k9 : wbound; \
            } \
        } \
    } while (0)
        #pragma unroll 1
        for (int i = 0; i < 32; i += 4) {       // 8 iters, 4 loads in flight
            float4 p0 = cl[(i+0)*256 + tid];
            float4 p1 = cl[(i+1)*256 + tid];
            float4 p2 = cl[(i+2)*256 + tid];
            float4 p3 = cl[(i+3)*256 + tid];
            BPROC(p0, (i+0)*256 + tid);
            BPROC(p1, (i+1)*256 + tid);
            BPROC(p2, (i+2)*256 + tid);
            BPROC(p3, (i+3)*256 + tid);
            // refresh wave bound: min over 64 lanes of own 10th, low word
            // forced to 1s (dd-ties pass -> exact).
            unsigned long long wm = k9;
            #pragma unroll
            for (int off = 1; off < 64; off <<= 1) {
                unsigned long long o = __shfl_xor(wm, off);
                wm = (o < wm) ? o : wm;
            }
            wbound = wm | 0xFFFFFFFFull;
            kgate = (k9 < wbound) ? k9 : wbound;
        }
#undef BPROC

        // per-wave 10-round extraction merge: exact wave top-10, ascending,
        // identical in all 64 lanes (sentinel ties shift all owners — safe).
        unsigned long long fin[KNN];
        #pragma unroll
        for (int r = 0; r < KNN; ++r) {
            unsigned long long m = keys[0];
            #pragma unroll
            for (int off = 1; off < 64; off <<= 1) {
                unsigned long long o = __shfl_xor(m, off);
                m = (o < m) ? o : m;
            }
            fin[r] = m;
            if (keys[0] == m) {
                #pragma unroll
                for (int t = 0; t < KNN-1; ++t) keys[t] = keys[t+1];
                keys[KNN-1] = 0xFFFFFFFFFFFFFFFFull;
            }
        }

        if (lane == 0) {
            #pragma unroll
            for (int s = 0; s < KNN; ++s) wl[wid][s] = fin[s];
        }
        __syncthreads();
        if (tid == 0) {
            // 4-list head-pointer extraction merge (lists sorted ascending).
            // Real keys unique -> exactly one list advances; equal sentinels
            // advance together (reads precede advances; idx <= round <= 9).
            int i0 = 0, i1 = 0, i2 = 0, i3 = 0;
            unsigned long long outk[KNN];
            #pragma unroll
            for (int r = 0; r < KNN; ++r) {
                unsigned long long h0 = wl[0][i0], h1 = wl[1][i1];
                unsigned long long h2 = wl[2][i2], h3 = wl[3][i3];
                unsigned long long m01 = (h0 < h1) ? h0 : h1;
                unsigned long long m23 = (h2 < h3) ? h2 : h3;
                unsigned long long m   = (m01 < m23) ? m01 : m23;
                outk[r] = m;
                i0 += (h0 == m); i1 += (h1 == m);
                i2 += (h2 == m); i3 += (h3 == m);
            }
            float c[6];
            cov_compute(cl, outk, c);
            size_t o = ((size_t)pair*NN + qi)*2;
            Cov[o]   = make_float4(c[0], c[1], c[2], c[3]);
            Cov[o+1] = make_float4(c[4], c[5], 0.0f, 0.0f);
        }
        __syncthreads();                        // protect wl for next query
    }
}

// ---------------------------------------------------------------------------
// Kernel E (R19): fused eigh + loss, ONE eigh per thread over 2*BN threads.
// Thread 2k handles gt[k], thread 2k+1 handles pred[k]; normals exchanged
// in-wave via shfl_xor(1); even lanes compute 1-cos; block reduce; atomic.
// Identical eigh inputs -> bit-identical normals (summation grouping only).
// ---------------------------------------------------------------------------
__global__ __launch_bounds__(256) void eigh_loss_kernel(
    const float4* __restrict__ Cov, float* __restrict__ accum,
    unsigned* __restrict__ counter, float* __restrict__ out)
{
    int tid = threadIdx.x;
    int t = blockIdx.x * 256 + tid;            // 0..2*BN-1
    int k = t >> 1;                            // pair index 0..BN-1
    int cld = t & 1;                           // 0 = gt, 1 = pred
    size_t ci = ((size_t)(cld ? BN + k : k)) * 2;
    float4 a0 = Cov[ci], a1 = Cov[ci + 1];
    float n[3];
    eigh3_smallest(a0.x, a0.y, a0.z, a0.w, a1.x, a1.y, n);

    // exchange with partner lane (2k <-> 2k+1 always share a wave)
    float ox = __shfl_xor(n[0], 1);
    float oy = __shfl_xor(n[1], 1);
    float oz = __shfl_xor(n[2], 1);

    float v = 0.0f;
    if (cld == 0) {
        float gx=n[0], gy=n[1], gz=n[2];
        float hx=ox,  hy=oy,  hz=oz;
        float dot = fmaf(gx,hx,fmaf(gy,hy,gz*hz));
        float ng  = sqrtf(fmaf(gx,gx,fmaf(gy,gy,gz*gz)));
        float nh  = sqrtf(fmaf(hx,hx,fmaf(hy,hy,hz*hz)));
        float den = fmaxf(ng*nh, 1e-8f);
        v = 1.0f - dot/den;
    }

    __shared__ float red[256];
    red[tid] = v;                              // odd lanes contribute 0
    __syncthreads();
    for (int s = 128; s > 0; s >>= 1) {
        if (tid < s) red[tid] += red[tid+s];
        __syncthreads();
    }
    if (tid == 0) {
        atomicAdd(accum, red[0]);
        __threadfence();
        unsigned old = atomicAdd(counter, 1u);
        if (old == (unsigned)(2*BN/256 - 1)) {
            float tot = atomicAdd(accum, 0.0f);
            out[0] = tot * (1.0f/(float)BN);
        }
    }
}

// ---------------------------------------------------------------------------
extern "C" void kernel_launch(void* const* d_in, const int* in_sizes, int n_in,
                              void* d_out, int out_size, void* d_ws, size_t ws_size,
                              hipStream_t stream)
{
    (void)in_sizes; (void)n_in; (void)out_size; (void)ws_size;
    const float*    gt   = (const float*)d_in[0];
    const float*    pred = (const float*)d_in[1];
    const unsigned* idxw = (const unsigned*)d_in[2];
    float* out = (float*)d_out;

    char* w = (char*)d_ws;
    float4* P4   = (float4*)w;                         w += (size_t)2*BN*16;   // 1 MB
    float4* S    = (float4*)w;                         w += (size_t)2*BN*16;   // 1 MB
    int*    hist = (int*)w;                            w += (size_t)8*NCELLS*4;   // 1 MB
    int2*   combo = (int2*)w;                          w += (size_t)8*NCELLS*8;   // 2 MB
    float4* Cov  = (float4*)w;                         w += (size_t)2*BN*32;   // 2 MB
    float*  accum = (float*)w;                         w += 16;
    unsigned* counter = (unsigned*)(accum + 1);
    int*    ovf_count = (int*)(accum + 2);
    int*    ovf  = (int*)w;                            w += (size_t)2*BN*4;    // 0.25 MB
    unsigned long long* ovf_key = (unsigned long long*)w;  w += (size_t)2*BN*8; // 0.5 MB

    hipMemsetAsync(hist, 0, (size_t)8*NCELLS*4, stream);
    hipLaunchKernelGGL(prep_kernel,    dim3(2*BN/256), dim3(256),  0, stream,
                       gt, pred, idxw, P4, hist, accum, counter, ovf_count);
    hipLaunchKernelGGL(scan_kernel,    dim3(8),        dim3(1024), 0, stream,
                       hist, combo);
    hipLaunchKernelGGL(scatter_kernel, dim3(2*BN/256), dim3(256),  0, stream,
                       P4, hist, combo, S);
    hipLaunchKernelGGL(knn_main_kernel, dim3(2*BN*4/64), dim3(64), 0, stream,
                       P4, S, combo, Cov, ovf, ovf_key, ovf_count);
    hipLaunchKernelGGL(brute_kernel,   dim3(BRUTE_BLOCKS), dim3(256), 0, stream,
                       P4, ovf, ovf_key, ovf_count, Cov);
    hipLaunchKernelGGL(eigh_loss_kernel, dim3(2*BN/256), dim3(256), 0, stream,
                       Cov, accum, counter, out);
}

// Round 8
// 257.407 us; speedup vs baseline: 1.0537x; 1.0537x over previous
//
#include <hip/hip_runtime.h>
#include <math.h>

#define BB   4
#define NN   8192
#define BN   (BB*NN)       // 32768 points per cloud-set; 8 clouds of 8192 total
#define KNN  10
#define G    32            // grid cells per dim
#define NCELLS (G*G*G)     // 32768 cells per cloud
#define GRID_LO (-5.0f)
#define H    0.3125f       // 10/32
#define INV_H 3.2f
#define RCAP 2             // rho<=2 region; beyond -> brute overflow

#define SEPS    5.9604645e-8f        // slamch('E') = 2^-24
#define SEPS2   (SEPS*SEPS)
#define SSAFMIN 1.1754944e-38f

__device__ __forceinline__ int cellc(float v) {
    int c = (int)floorf((v - GRID_LO) * INV_H);
    return min(G - 1, max(0, c));
}

// ---------------------------------------------------------------------------
// Kernel A: build P4[8][8192] = (x,y,z, bitcast orig-idx); clouds 0-3 = gt
// batches, 4-7 = pred[idx12] batches. Histogram cells + zero accumulators.
// ---------------------------------------------------------------------------
__global__ __launch_bounds__(256) void prep_kernel(
    const float* __restrict__ gt, const float* __restrict__ pred,
    const unsigned* __restrict__ idxw, float4* __restrict__ P4,
    int* __restrict__ hist, float* __restrict__ accum,
    unsigned* __restrict__ counter, int* __restrict__ ovf_count)
{
    __shared__ int s_is32;
    int tid = threadIdx.x;
    if (tid == 0) s_is32 = 0;
    __syncthreads();
    if (idxw[2*tid + 1] != 0u) s_is32 = 1;   // int64 => all high words 0
    __syncthreads();
    bool is64 = (s_is32 == 0);

    if (blockIdx.x == 0 && tid == 0) {
        *accum = 0.0f; *counter = 0u; *ovf_count = 0;
    }

    int point = blockIdx.x * 256 + tid;        // 0 .. 2*BN-1
    int pair = point >> 13;                    // 0..7
    int r    = point & (NN - 1);               // idx within cloud
    float x, y, z;
    if (point < BN) {
        const float* s = gt + (size_t)point*3;
        x = s[0]; y = s[1]; z = s[2];
    } else {
        int rr = point - BN;
        int b = rr >> 13;
        unsigned idx = is64 ? idxw[2*(size_t)rr] : idxw[rr];
        const float* s = pred + ((size_t)b*NN + idx)*3;
        x = s[0]; y = s[1]; z = s[2];
    }
    P4[point] = make_float4(x, y, z, __int_as_float(r));
    int cell = (cellc(z)*G + cellc(y))*G + cellc(x);
    atomicAdd(&hist[(size_t)pair*NCELLS + cell], 1);
}

// ---------------------------------------------------------------------------
// Kernel B: per-cloud exclusive scan -> combo[c] = int2(start, count).
// ---------------------------------------------------------------------------
__global__ __launch_bounds__(1024) void scan_kernel(
    const int* __restrict__ hist, int2* __restrict__ combo)
{
    int cloud = blockIdx.x;
    int tid = threadIdx.x;
    int lane = tid & 63, wid = tid >> 6;
    const int* h = hist + (size_t)cloud * NCELLS;
    int2* cb = combo + (size_t)cloud * NCELLS;

    int loc[32];
    int base = tid * 32;
    const int4* h4 = (const int4*)(h + base);
    int sum = 0;
    #pragma unroll
    for (int i = 0; i < 8; ++i) {
        int4 a = h4[i];
        loc[4*i+0] = a.x; loc[4*i+1] = a.y; loc[4*i+2] = a.z; loc[4*i+3] = a.w;
        sum += a.x + a.y + a.z + a.w;
    }
    // inclusive wave scan of sums
    int v = sum;
    #pragma unroll
    for (int off = 1; off < 64; off <<= 1) {
        int o = __shfl_up(v, off, 64);
        if (lane >= off) v += o;
    }
    __shared__ int ws[16], wsx[16];
    if (lane == 63) ws[wid] = v;
    __syncthreads();
    if (tid < 16) {
        int acc = 0;
        for (int i = 0; i < tid; ++i) acc += ws[i];
        wsx[tid] = acc;
    }
    __syncthreads();
    int run = (v - sum) + wsx[wid];            // exclusive prefix for this thread

    int4* cb4 = (int4*)(cb + base);            // 2 cells per int4 store
    #pragma unroll
    for (int i = 0; i < 16; ++i) {
        int4 o;
        o.x = run; o.y = loc[2*i];     run += loc[2*i];
        o.z = run; o.w = loc[2*i+1];   run += loc[2*i+1];
        cb4[i] = o;
    }
}

// ---------------------------------------------------------------------------
// Kernel C: scatter points into cell-sorted S.
// ---------------------------------------------------------------------------
__global__ __launch_bounds__(256) void scatter_kernel(
    const float4* __restrict__ P4, int* __restrict__ hist,
    const int2* __restrict__ combo, float4* __restrict__ S)
{
    int point = blockIdx.x * 256 + threadIdx.x;
    float4 p = P4[point];
    int pair = point >> 13;
    int cell = (cellc(p.z)*G + cellc(p.y))*G + cellc(p.x);
    int old = atomicSub(&hist[(size_t)pair*NCELLS + cell], 1);
    int pos = combo[(size_t)pair*NCELLS + cell].x + old - 1;
    S[(size_t)pair*NN + pos] = p;
}

// ---------------------------------------------------------------------------
// LAPACK ssyevd 3x3 path: ssytrd('L') + sorgtr + ssteqr('V'). Sign-faithful.
// (verified absmax 0.0 in rounds 2-18 — do not touch)
// ---------------------------------------------------------------------------
__device__ __forceinline__ float f_sign(float a, float b) {
    return copysignf(a, b);
}
__device__ __forceinline__ float slapy2(float x, float y) {
#pragma clang fp contract(off)
    float xa = fabsf(x), ya = fabsf(y);
    float w = fmaxf(xa, ya), z = fminf(xa, ya);
    if (z == 0.0f) return w;
    float t = z / w;
    return w * __fsqrt_rn(1.0f + t*t);
}
__device__ __forceinline__ void slartg_(float f, float g, float* cs, float* sn, float* r) {
#pragma clang fp contract(off)
    if (g == 0.0f)      { *cs = 1.0f; *sn = 0.0f; *r = f; }
    else if (f == 0.0f) { *cs = 0.0f; *sn = f_sign(1.0f, g); *r = fabsf(g); }
    else {
        float f1 = fabsf(f);
        float d = __fsqrt_rn(f*f + g*g);
        float p = 1.0f / d;
        *cs = f1 * p;
        *sn = g * f_sign(p, f);
        *r  = f_sign(d, f);
    }
}
__device__ void slaev2_(float a, float b, float c,
                        float* rt1, float* rt2, float* cs1, float* sn1) {
#pragma clang fp contract(off)
    float sm = a + c, df = a - c;
    float adf = fabsf(df);
    float tb = b + b;
    float ab = fabsf(tb);
    float acmx, acmn;
    if (fabsf(a) > fabsf(c)) { acmx = a; acmn = c; } else { acmx = c; acmn = a; }
    float rt;
    if (adf > ab)      { float t = ab/adf; rt = adf*__fsqrt_rn(1.0f + t*t); }
    else if (adf < ab) { float t = adf/ab; rt = ab*__fsqrt_rn(1.0f + t*t); }
    else               { rt = ab*__fsqrt_rn(2.0f); }
    int sgn1;
    if (sm < 0.0f)      { *rt1 = 0.5f*(sm - rt); sgn1 = -1;
                          *rt2 = (acmx / *rt1)*acmn - (b / *rt1)*b; }
    else if (sm > 0.0f) { *rt1 = 0.5f*(sm + rt); sgn1 = 1;
                          *rt2 = (acmx / *rt1)*acmn - (b / *rt1)*b; }
    else                { *rt1 = 0.5f*rt; *rt2 = -0.5f*rt; sgn1 = 1; }
    float cs; int sgn2;
    if (df >= 0.0f) { cs = df + rt; sgn2 = 1; } else { cs = df - rt; sgn2 = -1; }
    float acs = fabsf(cs);
    float c1, s1;
    if (acs > ab) { float ct = -tb/cs; s1 = 1.0f/__fsqrt_rn(1.0f + ct*ct); c1 = ct*s1; }
    else {
        if (ab == 0.0f) { c1 = 1.0f; s1 = 0.0f; }
        else { float tn = -cs/tb; c1 = 1.0f/__fsqrt_rn(1.0f + tn*tn); s1 = tn*c1; }
    }
    if (sgn1 == sgn2) { float tn = c1; c1 = -s1; s1 = tn; }
    *cs1 = c1; *sn1 = s1;
}

__device__ void eigh3_smallest(float c00, float c01, float c02,
                               float c11, float c12, float c22, float nv[3])
{
#pragma clang fp contract(off)
    // ---- ssytrd('L') ----
    float d[4], e[3], z[4][4];
    float tau1, v2 = 0.0f;
    float e1, d2, d3, e2;
    float alpha = c01, x = c02;
    if (x == 0.0f) {
        tau1 = 0.0f; e1 = alpha;
        d2 = c11; d3 = c22; e2 = c12;
    } else {
        float beta = -f_sign(slapy2(alpha, fabsf(x)), alpha);
        tau1 = (beta - alpha) / beta;
        v2 = x / (alpha - beta);
        e1 = beta;
        float w1 = tau1*(c11 + c12*v2);
        float w2 = tau1*(c12 + c22*v2);
        float al = -0.5f*tau1*(w1 + w2*v2);
        w1 = w1 + al;
        w2 = w2 + al*v2;
        d2 = (c11 - w1) - w1;
        e2 = (c12 - v2*w1) - w2;
        d3 = (c22 - v2*w2) - w2*v2;
    }
    d[1] = c00; d[2] = d2; d[3] = d3;
    e[1] = e1;  e[2] = e2;
    z[1][1] = 1.0f; z[1][2] = 0.0f; z[1][3] = 0.0f;
    z[2][1] = 0.0f; z[3][1] = 0.0f;
    z[2][2] = 1.0f - tau1;
    float mtv = -tau1*v2;
    z[2][3] = mtv; z[3][2] = mtv;
    z[3][3] = 1.0f + mtv*v2;

    // ---- ssteqr('V', 3) ----
    const int n = 3, nm1 = 2;
    int l1 = 1, jtot = 0;
    const int nmaxit = 90;
    float cw[3], sw[3];
    int guard = 0;
    while (guard++ < 64) {
        if (l1 > n) break;
        if (l1 > 1) e[l1-1] = 0.0f;
        int m = n;
        if (l1 <= nm1) {
            for (int mi = l1; mi <= nm1; ++mi) {
                float tst = fabsf(e[mi]);
                if (tst == 0.0f) { m = mi; break; }
                if (tst <= (__fsqrt_rn(fabsf(d[mi]))*__fsqrt_rn(fabsf(d[mi+1])))*SEPS) {
                    e[mi] = 0.0f; m = mi; break;
                }
            }
        }
        int l = l1;
        int lsv = l, lend = m, lendsv = lend;
        l1 = m + 1;
        if (lend == l) continue;
        if (fabsf(d[lend]) < fabsf(d[l])) { lend = lsv; l = lendsv; }

        if (lend > l) {
            // QL
            while (true) {
                int m_ = lend;
                if (l != lend) {
                    for (int mi = l; mi <= lend-1; ++mi) {
                        float em = e[mi];
                        float tst = em*em;
                        if (tst <= (SEPS2*fabsf(d[mi]))*fabsf(d[mi+1]) + SSAFMIN) { m_ = mi; break; }
                    }
                }
                if (m_ < lend) e[m_] = 0.0f;
                float p = d[l];
                if (m_ == l) {
                    d[l] = p; l = l + 1;
                    if (l <= lend) continue; else break;
                }
                if (m_ == l + 1) {
                    float rt1, rt2, cc, ss;
                    slaev2_(d[l], e[l], d[l+1], &rt1, &rt2, &cc, &ss);
                    for (int i = 1; i <= 3; ++i) {
                        float tmp = z[i][l+1];
                        z[i][l+1] = cc*tmp - ss*z[i][l];
                        z[i][l]   = ss*tmp + cc*z[i][l];
                    }
                    d[l] = rt1; d[l+1] = rt2; e[l] = 0.0f;
                    l = l + 2;
                    if (l <= lend) continue; else break;
                }
                if (jtot == nmaxit) break;
                jtot++;
                float g = (d[l+1] - p) / (2.0f*e[l]);
                float r = slapy2(g, 1.0f);
                g = d[m_] - p + (e[l] / (g + f_sign(r, g)));
                float s = 1.0f, c = 1.0f;
                p = 0.0f;
                for (int i = m_-1; i >= l; --i) {
                    float f = s*e[i];
                    float b = c*e[i];
                    slartg_(g, f, &c, &s, &r);
                    if (i != m_-1) e[i+1] = r;
                    g = d[i+1] - p;
                    r = (d[i] - g)*s + (2.0f*c)*b;
                    p = s*r;
                    d[i+1] = g + p;
                    g = c*r - b;
                    cw[i] = c; sw[i] = -s;
                }
                for (int j = m_-1; j >= l; --j) {
                    float cc = cw[j], ss = sw[j];
                    for (int i = 1; i <= 3; ++i) {
                        float tmp = z[i][j+1];
                        z[i][j+1] = cc*tmp - ss*z[i][j];
                        z[i][j]   = ss*tmp + cc*z[i][j];
                    }
                }
                d[l] = d[l] - p;
                e[l] = g;
            }
        } else {
            // QR
            while (true) {
                int m_ = lend;
                if (l != lend) {
                    for (int mi = l; mi >= lend+1; --mi) {
                        float em = e[mi-1];
                        float tst = em*em;
                        if (tst <= (SEPS2*fabsf(d[mi]))*fabsf(d[mi-1]) + SSAFMIN) { m_ = mi; break; }
                    }
                }
                if (m_ > lend) e[m_-1] = 0.0f;
                float p = d[l];
                if (m_ == l) {
                    d[l] = p; l = l - 1;
                    if (l >= lend) continue; else break;
                }
                if (m_ == l - 1) {
                    float rt1, rt2, cc, ss;
                    slaev2_(d[l-1], e[l-1], d[l], &rt1, &rt2, &cc, &ss);
                    for (int i = 1; i <= 3; ++i) {
                        float tmp = z[i][l];
                        z[i][l]   = cc*tmp - ss*z[i][l-1];
                        z[i][l-1] = ss*tmp + cc*z[i][l-1];
                    }
                    d[l-1] = rt1; d[l] = rt2; e[l-1] = 0.0f;
                    l = l - 2;
                    if (l >= lend) continue; else break;
                }
                if (jtot == nmaxit) break;
                jtot++;
                float g = (d[l-1] - p) / (2.0f*e[l-1]);
                float r = slapy2(g, 1.0f);
                g = d[m_] - p + (e[l-1] / (g + f_sign(r, g)));
                float s = 1.0f, c = 1.0f;
                p = 0.0f;
                for (int i = m_; i <= l-1; ++i) {
                    float f = s*e[i];
                    float b = c*e[i];
                    slartg_(g, f, &c, &s, &r);
                    if (i != m_) e[i-1] = r;
                    g = d[i] - p;
                    r = (d[i+1] - g)*s + (2.0f*c)*b;
                    p = s*r;
                    d[i] = g + p;
                    g = c*r - b;
                    cw[i] = c; sw[i] = s;
                }
                for (int j = m_; j <= l-1; ++j) {
                    float cc = cw[j], ss = sw[j];
                    for (int i = 1; i <= 3; ++i) {
                        float tmp = z[i][j+1];
                        z[i][j+1] = cc*tmp - ss*z[i][j];
                        z[i][j]   = ss*tmp + cc*z[i][j];
                    }
                }
                d[l] = d[l] - p;
                e[l-1] = g;
            }
        }
    }
    for (int ii = 2; ii <= 3; ++ii) {
        int i = ii - 1, k = i;
        float p = d[i];
        for (int j = ii; j <= 3; ++j) if (d[j] < p) { k = j; p = d[j]; }
        if (k != i) {
            d[k] = d[i]; d[i] = p;
            for (int r2 = 1; r2 <= 3; ++r2) {
                float t = z[r2][i]; z[r2][i] = z[r2][k]; z[r2][k] = t;
            }
        }
    }
    nv[0] = z[1][1]; nv[1] = z[2][1]; nv[2] = z[3][1];
}

// Covariance of the sorted 10-neighborhood (same op order as rounds 2-18).
__device__ void cov_compute(const float4* __restrict__ cl,
                            const unsigned long long keys[KNN], float c[6])
{
#pragma clang fp contract(off)
    float px[KNN], py[KNN], pz[KNN];
    float sx = 0.f, sy = 0.f, sz = 0.f;
    #pragma unroll
    for (int s = 0; s < KNN; ++s) {
        int ni = (int)(unsigned)(keys[s] & 0xFFFFFFFFull);
        float4 np = cl[ni];
        px[s] = np.x; py[s] = np.y; pz[s] = np.z;
        sx = sx + px[s]; sy = sy + py[s]; sz = sz + pz[s];
    }
    float mx = sx / 10.0f, my = sy / 10.0f, mz = sz / 10.0f;
    float c00=0.f,c01=0.f,c02=0.f,c11=0.f,c12=0.f,c22=0.f;
    #pragma unroll
    for (int s = 0; s < KNN; ++s) {
        float dx = px[s]-mx, dy = py[s]-my, dz = pz[s]-mz;
        c00 = c00 + dx*dx; c01 = c01 + dx*dy; c02 = c02 + dx*dz;
        c11 = c11 + dy*dy; c12 = c12 + dy*dz; c22 = c22 + dz*dz;
    }
    c[0] = c00/10.0f; c[1] = c01/10.0f; c[2] = c02/10.0f;
    c[3] = c11/10.0f; c[4] = c12/10.0f; c[5] = c22/10.0f;
}

// ---------------------------------------------------------------------------
// Insert: gate = min(own 10th, quad bound). Dropping candidates >= the quad
// bound is exact: some lane already holds 10 strictly-better keys. In phase 2
// qbK is ~0ull so the gate degenerates to the (exact) own 10th.
// ---------------------------------------------------------------------------
#define PROC(p) do { \
    float ddx = qx - (p).x, ddy = qy - (p).y, ddz = qz - (p).z; \
    float dd = fmaf(ddz, ddz, fmaf(ddy, ddy, ddx*ddx)); \
    unsigned long long key = \
        ((unsigned long long)__float_as_uint(dd) << 32) | \
        (unsigned)__float_as_int((p).w); \
    if (key < kgate) { \
        unsigned long long ck = key; \
        _Pragma("unroll") \
        for (int s = 0; s < KNN; ++s) { \
            unsigned long long ok2 = keys[s]; \
            bool sw = ok2 > ck; \
            keys[s] = sw ? ck : ok2; \
            ck      = sw ? ok2 : ck; \
        } \
        k9 = keys[KNN-1]; \
        kgate = (k9 < qbK) ? k9 : qbK; \
    } \
} while (0)

// R24 cooperative stride-4 segment walk: the QUAD jointly covers [bgn,end);
// lane sub takes elements bgn+sub, +4, +8, ... Perfect quad balance (steps =
// ceil(len/4), no per-lane row raggedness) and the quad's 4 loads are one
// contiguous 64B chunk (4x fewer cache lines per step than per-lane rows).
// Disjointness across lanes preserved -> per-lane exact reservoirs.
#define SEGPROC(bgn, end) do { \
    int _j = (bgn) + sub, _je = (end); \
    for (; _j + 4 < _je; _j += 8) { \
        float4 _p0 = cs[_j]; float4 _p1 = cs[_j+4]; \
        PROC(_p0); PROC(_p1); \
    } \
    if (_j < _je) { float4 _p0 = cs[_j]; PROC(_p0); } \
} while (0)

// quad-min of the four lanes' current 10th keys; low word forced to all-ones
// so ties on the distance bits still pass the gate (tie-exact).
#define QEXCH() do { \
    unsigned long long _o1 = __shfl_xor(k9, 1, 4); \
    unsigned long long _m1 = (_o1 < k9) ? _o1 : k9; \
    unsigned long long _o2 = __shfl_xor(_m1, 2, 4); \
    unsigned long long _qm = (_o2 < _m1) ? _o2 : _m1; \
    qbK = _qm | 0xFFFFFFFFull; \
    kgate = (k9 < qbK) ? k9 : qbK; \
} while (0)

// R24 quad EXTRACTION merge: 10 rounds; per round a 2-stage u64-min butterfly
// finds the global min of the 4 sorted lists, every lane records it, every
// lane whose head equals it shifts down (shared keys collapse -> natural
// dedupe). Exact top-10 of the union, ascending, IDENTICAL in all 4 lanes.
#define QMERGE() do { \
    unsigned long long fin[KNN]; \
    _Pragma("unroll") \
    for (int r = 0; r < KNN; ++r) { \
        unsigned long long m = keys[0]; \
        unsigned long long _o1 = __shfl_xor(m, 1, 4); m = (_o1 < m) ? _o1 : m; \
        unsigned long long _o2 = __shfl_xor(m, 2, 4); m = (_o2 < m) ? _o2 : m; \
        fin[r] = m; \
        bool own = (keys[0] == m); \
        _Pragma("unroll") \
        for (int t = 0; t < KNN-1; ++t) keys[t] = own ? keys[t+1] : keys[t]; \
        keys[KNN-1] = own ? 0xFFFFFFFFFFFFFFFFull : keys[KNN-1]; \
    } \
    _Pragma("unroll") \
    for (int s = 0; s < KNN; ++s) keys[s] = fin[s]; \
    k9 = keys[KNN-1]; \
} while (0)

// ---------------------------------------------------------------------------
// Kernel D (R27 = R25 exactly, the measured-63.4us config): grid 10-NN, FOUR
// lanes per query, 256-thread blocks, R23 5<->5 block swizzle. Cooperative
// stride-4 cube walk, quad extraction-merge -> exact cube top-10 -> exact
// phase-2 skip + tight worstM pruning -> cooperative shell walk -> final
// extraction-merge. Bit-identical output.
// (R26's 64-thread-block experiment is reverted: total regressed 233->271
//  and per-kernel attribution was ambiguous; re-baselining on R25.)
// ---------------------------------------------------------------------------
__global__ __launch_bounds__(256) void knn_main_kernel(
    const float4* __restrict__ P4, const float4* __restrict__ S,
    const int2* __restrict__ combo, float4* __restrict__ Cov,
    int* __restrict__ ovf, unsigned long long* __restrict__ ovf_key,
    int* __restrict__ ovf_count)
{
    int b = blockIdx.x;                         // 0..1023
    int bb = ((b & 31) << 5) | (b >> 5);        // 5<->5 bit swap (bijective)
    int tidg = bb * 256 + threadIdx.x;          // 0..262143
    int qid  = tidg >> 2;                       // 0..65535
    int sub  = tidg & 3;
    int pair = qid >> 13;                       // 8 clouds
    int spos = qid & (NN - 1);                  // sorted position
    const float4* __restrict__ cl = P4 + (size_t)pair * NN;
    const float4* __restrict__ cs = S  + (size_t)pair * NN;
    const int2*   __restrict__ cb = combo + (size_t)pair * NCELLS;

    float4 q = cs[spos];
    float qx = q.x, qy = q.y, qz = q.z;
    int qi = __float_as_int(q.w);               // original index in cloud
    int qcx = cellc(qx), qcy = cellc(qy), qcz = cellc(qz);

    unsigned long long keys[KNN];
    #pragma unroll
    for (int s = 0; s < KNN; ++s) keys[s] = 0xFFFFFFFFFFFFFFFFull;
    unsigned long long k9    = 0xFFFFFFFFFFFFFFFFull;
    unsigned long long qbK   = 0xFFFFFFFFFFFFFFFFull;
    unsigned long long kgate = 0xFFFFFFFFFFFFFFFFull;

    // ---- phase 1: rho<=1 cube = 9 (z,y) rows, center-out order so gates
    // tighten early; QEXCH between rows shares the quad bound.
    int x0 = max(qcx - 1, 0), x1 = min(qcx + 1, G - 1);
    {
        const int DZ9[9] = { 0,  0,  0, -1,  1, -1, -1,  1,  1};
        const int DY9[9] = { 0,  1, -1,  0,  0, -1,  1, -1,  1};
        int rb[9], re[9];
        #pragma unroll
        for (int r = 0; r < 9; ++r) {
            int zz = qcz + DZ9[r], yy = qcy + DY9[r];
            rb[r] = 0; re[r] = 0;
            if ((unsigned)zz < G && (unsigned)yy < G) {
                int cbase = (zz*G + yy)*G;
                int2 a  = cb[cbase + x0];
                int2 b2 = cb[cbase + x1];
                rb[r] = a.x; re[r] = b2.x + b2.y;
            }
        }
        #pragma unroll
        for (int r = 0; r < 9; ++r) {
            SEGPROC(rb[r], re[r]);
            if (r == 0 || r == 2 || r == 4 || r == 6) QEXCH();
        }
    }

    // ---- quad extraction-merge -> exact cube top-10, identical in all lanes
    QMERGE();
    const unsigned long long k9M = k9;          // exact cube 10th (u64 key)
    float worstM = __uint_as_float((unsigned)(k9M >> 32)); // NaN if <10 found

    // ---- phase 2: rho=2 shell. Exterior of the cube is >= H from q, so
    // skip iff H^2 > worstM is EXACT (NaN-safe: NaN -> walk shell).
    bool skip = (H*H > worstM);                 // quad-uniform (worstM shared)

    qbK   = 0xFFFFFFFFFFFFFFFFull;              // phase-2 gate = own 10th
    kgate = k9;
    if (!skip) {
        int xs0 = max(qcx - 2, 0), xs1 = min(qcx + 2, G - 1);
        // 16 outer rows; box test redundant in all 4 lanes (same q -> same
        // result, quad-uniform branch), then cooperative stride-4 walk.
        const int SZ16[16] = {-2,-2,-2,-2,-2,  2, 2, 2, 2, 2, -1,-1, 0, 0, 1, 1};
        const int SY16[16] = {-2,-1, 0, 1, 2, -2,-1, 0, 1, 2, -2, 2,-2, 2,-2, 2};
        #pragma unroll
        for (int r = 0; r < 16; ++r) {
            int zz = qcz + SZ16[r], yy = qcy + SY16[r];
            if ((unsigned)zz < G && (unsigned)yy < G) {
                float loy = fmaf((float)yy, H, GRID_LO);
                float loz = fmaf((float)zz, H, GRID_LO);
                float py = fmaxf(0.0f, fmaxf(loy - qy, qy - (loy + H)));
                float pz = fmaxf(0.0f, fmaxf(loz - qz, qz - (loz + H)));
                float pyz = fmaf(pz, pz, py*py);
                if (!(pyz > worstM)) {
                    int cbase = (zz*G + yy)*G;
                    int2 a  = cb[cbase + xs0];
                    int2 b2 = cb[cbase + xs1];
                    SEGPROC(a.x, b2.x + b2.y);
                }
            }
        }
        // 18 isolated cells (|dz|<=1,|dy|<=1, dx=+/-2)
        const int CZ18[18] = {-1,-1,-1,-1,-1,-1,  0, 0, 0, 0, 0, 0,  1, 1, 1, 1, 1, 1};
        const int CY18[18] = {-1,-1, 0, 0, 1, 1, -1,-1, 0, 0, 1, 1, -1,-1, 0, 0, 1, 1};
        const int CX18[18] = {-2, 2,-2, 2,-2, 2, -2, 2,-2, 2,-2, 2, -2, 2,-2, 2,-2, 2};
        #pragma unroll
        for (int r = 0; r < 18; ++r) {
            int zz = qcz + CZ18[r], yy = qcy + CY18[r], xx = qcx + CX18[r];
            if ((unsigned)zz < G && (unsigned)yy < G && (unsigned)xx < G) {
                float lox = fmaf((float)xx, H, GRID_LO);
                float loy = fmaf((float)yy, H, GRID_LO);
                float loz = fmaf((float)zz, H, GRID_LO);
                float px = fmaxf(0.0f, fmaxf(lox - qx, qx - (lox + H)));
                float py = fmaxf(0.0f, fmaxf(loy - qy, qy - (loy + H)));
                float pz = fmaxf(0.0f, fmaxf(loz - qz, qz - (loz + H)));
                float m2 = fmaf(pz, pz, fmaf(py, py, px*px));
                if (!(m2 > worstM)) {
                    int2 a = cb[(zz*G + yy)*G + xx];
                    SEGPROC(a.x, a.x + a.y);
                }
            }
        }
    }

    // ---- final: extraction-merge again, but only if some lane inserted a
    // shell candidate (every successful insert strictly lowers k9). Shared
    // cube survivors are held by all 4 lanes -> all owners shift in the same
    // round -> natural exact dedupe. skip and ch are quad-uniform.
    if (!skip) {
        int ch = (k9 != k9M) ? 1 : 0;
        ch |= __shfl_xor(ch, 1, 4);
        ch |= __shfl_xor(ch, 2, 4);
        if (ch) QMERGE();
    }
    float worst_m = __uint_as_float((unsigned)(k9 >> 32));

    // resolved iff cells beyond the rho<=2 region (gap >= 2H) cannot contribute
    float bf = (float)RCAP * H;
    bool resolved = (bf*bf > worst_m);          // strict; NaN (unfilled) -> false
    if (resolved && sub == 0) {
        float c[6];
        cov_compute(cl, keys, c);               // sub==0 only: 1/4 gather loads
        size_t o = ((size_t)pair*NN + qi)*2;
        Cov[o]   = make_float4(c[0], c[1], c[2], c[3]);
        Cov[o+1] = make_float4(c[4], c[5], 0.0f, 0.0f);
    } else if (!resolved && sub == 0) {
        int pos = atomicAdd(ovf_count, 1);
        ovf[pos] = (pair << 13) | qi;
        ovf_key[pos] = k9;      // exact 10th over examined set: valid upper
    }                           // bound on the true 10th key
}

// ---------------------------------------------------------------------------
// Kernel D2 (R27): brute-force overflow, ONE BLOCK per query, blocks shrunk
// 256 -> 128 threads. WHY: residency cap was 8 blocks/CU (2048 threads), so
// ~2240 queries needed TWO residency rounds regardless of grid size (R26's
// grid bump was a no-op; its wave-bound refresh regressed and is dropped).
// At 128 thr/block the cap is min(16 thr-limited, ~14 VGPR-limited) blocks/CU
// -> ~3584 resident >= 2240 -> ONE round. Per-thread scan doubles (64
// candidates, 16 iters) but merge/sync/cov are fixed costs and the cross-wave
// LDS merge shrinks 4 -> 2 lists. Exactness: partition across threads is
// irrelevant — extraction merges emit the exact top-10 of the union in
// ascending order (same list as any partition) => bit-identical cov.
// ---------------------------------------------------------------------------
#define BRUTE_BLOCKS 4096
__global__ __launch_bounds__(128) void brute_kernel(
    const float4* __restrict__ P4, const int* __restrict__ ovf,
    const unsigned long long* __restrict__ ovf_key,
    const int* __restrict__ ovf_count, float4* __restrict__ Cov)
{
    __shared__ unsigned long long wl[2][KNN];
    int tid = threadIdx.x;
    int lane = tid & 63;
    int wid = tid >> 6;                         // 0..1
    int count = *ovf_count;

    for (int oi = blockIdx.x; oi < count; oi += BRUTE_BLOCKS) {
        int rec = ovf[oi];
        unsigned long long bound = ovf_key[oi];
        float bound_d = __uint_as_float((unsigned)(bound >> 32)); // NaN if unfilled
        int pair = rec >> 13;
        int qi = rec & (NN - 1);
        const float4* __restrict__ cl = P4 + (size_t)pair * NN;
        float4 q = cl[qi];
        float qx = q.x, qy = q.y, qz = q.z;

        unsigned long long keys[KNN];
        #pragma unroll
        for (int s = 0; s < KNN; ++s) keys[s] = 0xFFFFFFFFFFFFFFFFull;
        unsigned long long k9 = keys[KNN-1];

        // per-thread scan of a disjoint 1/128 slice (64 candidates), bound-
        // gated; ties at dd==bound_d pass (exact). Coalesced cl[i*128+tid].
#define BPROC(p, jj) do { \
        float ddx = qx - (p).x, ddy = qy - (p).y, ddz = qz - (p).z; \
        float dd = fmaf(ddz, ddz, fmaf(ddy, ddy, ddx*ddx)); \
        if (!(dd > bound_d)) { \
            unsigned long long key = \
                ((unsigned long long)__float_as_uint(dd) << 32) | (unsigned)(jj); \
            if (key < k9) { \
                unsigned long long ck = key; \
                _Pragma("unroll") \
                for (int s = 0; s < KNN; ++s) { \
                    unsigned long long ok2 = keys[s]; \
                    bool sw = ok2 > ck; \
                    keys[s] = sw ? ck : ok2; \
                    ck      = sw ? ok2 : ck; \
                } \
                k9 = keys[KNN-1]; \
            } \
        } \
    } while (0)
        #pragma unroll 1
        for (int i = 0; i < 64; i += 4) {       // 16 iters, 4 loads in flight
            float4 p0 = cl[(i+0)*128 + tid];
            float4 p1 = cl[(i+1)*128 + tid];
            float4 p2 = cl[(i+2)*128 + tid];
            float4 p3 = cl[(i+3)*128 + tid];
            BPROC(p0, (i+0)*128 + tid);
            BPROC(p1, (i+1)*128 + tid);
            BPROC(p2, (i+2)*128 + tid);
            BPROC(p3, (i+3)*128 + tid);
        }
#undef BPROC

        // per-wave 10-round extraction merge: exact wave top-10, ascending,
        // identical in all 64 lanes (sentinel ties shift all owners — safe).
        unsigned long long fin[KNN];
        #pragma unroll
        for (int r = 0; r < KNN; ++r) {
            unsigned long long m = keys[0];
            #pragma unroll
            for (int off = 1; off < 64; off <<= 1) {
                unsigned long long o = __shfl_xor(m, off);
                m = (o < m) ? o : m;
            }
            fin[r] = m;
            if (keys[0] == m) {
                #pragma unroll
                for (int t = 0; t < KNN-1; ++t) keys[t] = keys[t+1];
                keys[KNN-1] = 0xFFFFFFFFFFFFFFFFull;
            }
        }

        if (lane == 0) {
            #pragma unroll
            for (int s = 0; s < KNN; ++s) wl[wid][s] = fin[s];
        }
        __syncthreads();
        if (tid == 0) {
            // 2-list head-pointer extraction merge (lists sorted ascending).
            // Real keys unique -> exactly one list advances; equal sentinels
            // advance together (reads precede advances; idx <= round <= 9).
            int i0 = 0, i1 = 0;
            unsigned long long outk[KNN];
            #pragma unroll
            for (int r = 0; r < KNN; ++r) {
                unsigned long long h0 = wl[0][i0], h1 = wl[1][i1];
                unsigned long long m = (h0 < h1) ? h0 : h1;
                outk[r] = m;
                i0 += (h0 == m); i1 += (h1 == m);
            }
            float c[6];
            cov_compute(cl, outk, c);
            size_t o = ((size_t)pair*NN + qi)*2;
            Cov[o]   = make_float4(c[0], c[1], c[2], c[3]);
            Cov[o+1] = make_float4(c[4], c[5], 0.0f, 0.0f);
        }
        __syncthreads();                        // protect wl for next query
    }
}

// ---------------------------------------------------------------------------
// Kernel E (R19): fused eigh + loss, ONE eigh per thread over 2*BN threads.
// Thread 2k handles gt[k], thread 2k+1 handles pred[k]; normals exchanged
// in-wave via shfl_xor(1); even lanes compute 1-cos; block reduce; atomic.
// Identical eigh inputs -> bit-identical normals (summation grouping only).
// ---------------------------------------------------------------------------
__global__ __launch_bounds__(256) void eigh_loss_kernel(
    const float4* __restrict__ Cov, float* __restrict__ accum,
    unsigned* __restrict__ counter, float* __restrict__ out)
{
    int tid = threadIdx.x;
    int t = blockIdx.x * 256 + tid;            // 0..2*BN-1
    int k = t >> 1;                            // pair index 0..BN-1
    int cld = t & 1;                           // 0 = gt, 1 = pred
    size_t ci = ((size_t)(cld ? BN + k : k)) * 2;
    float4 a0 = Cov[ci], a1 = Cov[ci + 1];
    float n[3];
    eigh3_smallest(a0.x, a0.y, a0.z, a0.w, a1.x, a1.y, n);

    // exchange with partner lane (2k <-> 2k+1 always share a wave)
    float ox = __shfl_xor(n[0], 1);
    float oy = __shfl_xor(n[1], 1);
    float oz = __shfl_xor(n[2], 1);

    float v = 0.0f;
    if (cld == 0) {
        float gx=n[0], gy=n[1], gz=n[2];
        float hx=ox,  hy=oy,  hz=oz;
        float dot = fmaf(gx,hx,fmaf(gy,hy,gz*hz));
        float ng  = sqrtf(fmaf(gx,gx,fmaf(gy,gy,gz*gz)));
        float nh  = sqrtf(fmaf(hx,hx,fmaf(hy,hy,hz*hz)));
        float den = fmaxf(ng*nh, 1e-8f);
        v = 1.0f - dot/den;
    }

    __shared__ float red[256];
    red[tid] = v;                              // odd lanes contribute 0
    __syncthreads();
    for (int s = 128; s > 0; s >>= 1) {
        if (tid < s) red[tid] += red[tid+s];
        __syncthreads();
    }
    if (tid == 0) {
        atomicAdd(accum, red[0]);
        __threadfence();
        unsigned old = atomicAdd(counter, 1u);
        if (old == (unsigned)(2*BN/256 - 1)) {
            float tot = atomicAdd(accum, 0.0f);
            out[0] = tot * (1.0f/(float)BN);
        }
    }
}

// ---------------------------------------------------------------------------
extern "C" void kernel_launch(void* const* d_in, const int* in_sizes, int n_in,
                              void* d_out, int out_size, void* d_ws, size_t ws_size,
                              hipStream_t stream)
{
    (void)in_sizes; (void)n_in; (void)out_size; (void)ws_size;
    const float*    gt   = (const float*)d_in[0];
    const float*    pred = (const float*)d_in[1];
    const unsigned* idxw = (const unsigned*)d_in[2];
    float* out = (float*)d_out;

    char* w = (char*)d_ws;
    float4* P4   = (float4*)w;                         w += (size_t)2*BN*16;   // 1 MB
    float4* S    = (float4*)w;                         w += (size_t)2*BN*16;   // 1 MB
    int*    hist = (int*)w;                            w += (size_t)8*NCELLS*4;   // 1 MB
    int2*   combo = (int2*)w;                          w += (size_t)8*NCELLS*8;   // 2 MB
    float4* Cov  = (float4*)w;                         w += (size_t)2*BN*32;   // 2 MB
    float*  accum = (float*)w;                         w += 16;
    unsigned* counter = (unsigned*)(accum + 1);
    int*    ovf_count = (int*)(accum + 2);
    int*    ovf  = (int*)w;                            w += (size_t)2*BN*4;    // 0.25 MB
    unsigned long long* ovf_key = (unsigned long long*)w;  w += (size_t)2*BN*8; // 0.5 MB

    hipMemsetAsync(hist, 0, (size_t)8*NCELLS*4, stream);
    hipLaunchKernelGGL(prep_kernel,    dim3(2*BN/256), dim3(256),  0, stream,
                       gt, pred, idxw, P4, hist, accum, counter, ovf_count);
    hipLaunchKernelGGL(scan_kernel,    dim3(8),        dim3(1024), 0, stream,
                       hist, combo);
    hipLaunchKernelGGL(scatter_kernel, dim3(2*BN/256), dim3(256),  0, stream,
                       P4, hist, combo, S);
    hipLaunchKernelGGL(knn_main_kernel, dim3(2*BN*4/256), dim3(256), 0, stream,
                       P4, S, combo, Cov, ovf, ovf_key, ovf_count);
    hipLaunchKernelGGL(brute_kernel,   dim3(BRUTE_BLOCKS), dim3(128), 0, stream,
                       P4, ovf, ovf_key, ovf_count, Cov);
    hipLaunchKernelGGL(eigh_loss_kernel, dim3(2*BN/256), dim3(256), 0, stream,
                       Cov, accum, counter, out);
}

// Round 9
// 236.184 us; speedup vs baseline: 1.1484x; 1.0899x over previous
//
#include <hip/hip_runtime.h>
#include <math.h>

#define BB   4
#define NN   8192
#define BN   (BB*NN)       // 32768 points per cloud-set; 8 clouds of 8192 total
#define KNN  10
#define G    32            // grid cells per dim
#define NCELLS (G*G*G)     // 32768 cells per cloud
#define GRID_LO (-5.0f)
#define H    0.3125f       // 10/32
#define INV_H 3.2f
#define RCAP 2             // rho<=2 resolution for the fast path; phase 3 -> 3

#define SEPS    5.9604645e-8f        // slamch('E') = 2^-24
#define SEPS2   (SEPS*SEPS)
#define SSAFMIN 1.1754944e-38f

__device__ __forceinline__ int cellc(float v) {
    int c = (int)floorf((v - GRID_LO) * INV_H);
    return min(G - 1, max(0, c));
}

// ---------------------------------------------------------------------------
// Kernel A: build P4[8][8192] = (x,y,z, bitcast orig-idx); clouds 0-3 = gt
// batches, 4-7 = pred[idx12] batches. Histogram cells + zero accumulators.
// ---------------------------------------------------------------------------
__global__ __launch_bounds__(256) void prep_kernel(
    const float* __restrict__ gt, const float* __restrict__ pred,
    const unsigned* __restrict__ idxw, float4* __restrict__ P4,
    int* __restrict__ hist, float* __restrict__ accum,
    unsigned* __restrict__ counter, int* __restrict__ ovf_count)
{
    __shared__ int s_is32;
    int tid = threadIdx.x;
    if (tid == 0) s_is32 = 0;
    __syncthreads();
    if (idxw[2*tid + 1] != 0u) s_is32 = 1;   // int64 => all high words 0
    __syncthreads();
    bool is64 = (s_is32 == 0);

    if (blockIdx.x == 0 && tid == 0) {
        *accum = 0.0f; *counter = 0u; *ovf_count = 0;
    }

    int point = blockIdx.x * 256 + tid;        // 0 .. 2*BN-1
    int pair = point >> 13;                    // 0..7
    int r    = point & (NN - 1);               // idx within cloud
    float x, y, z;
    if (point < BN) {
        const float* s = gt + (size_t)point*3;
        x = s[0]; y = s[1]; z = s[2];
    } else {
        int rr = point - BN;
        int b = rr >> 13;
        unsigned idx = is64 ? idxw[2*(size_t)rr] : idxw[rr];
        const float* s = pred + ((size_t)b*NN + idx)*3;
        x = s[0]; y = s[1]; z = s[2];
    }
    P4[point] = make_float4(x, y, z, __int_as_float(r));
    int cell = (cellc(z)*G + cellc(y))*G + cellc(x);
    atomicAdd(&hist[(size_t)pair*NCELLS + cell], 1);
}

// ---------------------------------------------------------------------------
// Kernel B: per-cloud exclusive scan -> combo[c] = int2(start, count).
// ---------------------------------------------------------------------------
__global__ __launch_bounds__(1024) void scan_kernel(
    const int* __restrict__ hist, int2* __restrict__ combo)
{
    int cloud = blockIdx.x;
    int tid = threadIdx.x;
    int lane = tid & 63, wid = tid >> 6;
    const int* h = hist + (size_t)cloud * NCELLS;
    int2* cb = combo + (size_t)cloud * NCELLS;

    int loc[32];
    int base = tid * 32;
    const int4* h4 = (const int4*)(h + base);
    int sum = 0;
    #pragma unroll
    for (int i = 0; i < 8; ++i) {
        int4 a = h4[i];
        loc[4*i+0] = a.x; loc[4*i+1] = a.y; loc[4*i+2] = a.z; loc[4*i+3] = a.w;
        sum += a.x + a.y + a.z + a.w;
    }
    // inclusive wave scan of sums
    int v = sum;
    #pragma unroll
    for (int off = 1; off < 64; off <<= 1) {
        int o = __shfl_up(v, off, 64);
        if (lane >= off) v += o;
    }
    __shared__ int ws[16], wsx[16];
    if (lane == 63) ws[wid] = v;
    __syncthreads();
    if (tid < 16) {
        int acc = 0;
        for (int i = 0; i < tid; ++i) acc += ws[i];
        wsx[tid] = acc;
    }
    __syncthreads();
    int run = (v - sum) + wsx[wid];            // exclusive prefix for this thread

    int4* cb4 = (int4*)(cb + base);            // 2 cells per int4 store
    #pragma unroll
    for (int i = 0; i < 16; ++i) {
        int4 o;
        o.x = run; o.y = loc[2*i];     run += loc[2*i];
        o.z = run; o.w = loc[2*i+1];   run += loc[2*i+1];
        cb4[i] = o;
    }
}

// ---------------------------------------------------------------------------
// Kernel C: scatter points into cell-sorted S.
// ---------------------------------------------------------------------------
__global__ __launch_bounds__(256) void scatter_kernel(
    const float4* __restrict__ P4, int* __restrict__ hist,
    const int2* __restrict__ combo, float4* __restrict__ S)
{
    int point = blockIdx.x * 256 + threadIdx.x;
    float4 p = P4[point];
    int pair = point >> 13;
    int cell = (cellc(p.z)*G + cellc(p.y))*G + cellc(p.x);
    int old = atomicSub(&hist[(size_t)pair*NCELLS + cell], 1);
    int pos = combo[(size_t)pair*NCELLS + cell].x + old - 1;
    S[(size_t)pair*NN + pos] = p;
}

// ---------------------------------------------------------------------------
// LAPACK ssyevd 3x3 path: ssytrd('L') + sorgtr + ssteqr('V'). Sign-faithful.
// (verified absmax 0.0 in rounds 2-18 — do not touch)
// ---------------------------------------------------------------------------
__device__ __forceinline__ float f_sign(float a, float b) {
    return copysignf(a, b);
}
__device__ __forceinline__ float slapy2(float x, float y) {
#pragma clang fp contract(off)
    float xa = fabsf(x), ya = fabsf(y);
    float w = fmaxf(xa, ya), z = fminf(xa, ya);
    if (z == 0.0f) return w;
    float t = z / w;
    return w * __fsqrt_rn(1.0f + t*t);
}
__device__ __forceinline__ void slartg_(float f, float g, float* cs, float* sn, float* r) {
#pragma clang fp contract(off)
    if (g == 0.0f)      { *cs = 1.0f; *sn = 0.0f; *r = f; }
    else if (f == 0.0f) { *cs = 0.0f; *sn = f_sign(1.0f, g); *r = fabsf(g); }
    else {
        float f1 = fabsf(f);
        float d = __fsqrt_rn(f*f + g*g);
        float p = 1.0f / d;
        *cs = f1 * p;
        *sn = g * f_sign(p, f);
        *r  = f_sign(d, f);
    }
}
__device__ void slaev2_(float a, float b, float c,
                        float* rt1, float* rt2, float* cs1, float* sn1) {
#pragma clang fp contract(off)
    float sm = a + c, df = a - c;
    float adf = fabsf(df);
    float tb = b + b;
    float ab = fabsf(tb);
    float acmx, acmn;
    if (fabsf(a) > fabsf(c)) { acmx = a; acmn = c; } else { acmx = c; acmn = a; }
    float rt;
    if (adf > ab)      { float t = ab/adf; rt = adf*__fsqrt_rn(1.0f + t*t); }
    else if (adf < ab) { float t = adf/ab; rt = ab*__fsqrt_rn(1.0f + t*t); }
    else               { rt = ab*__fsqrt_rn(2.0f); }
    int sgn1;
    if (sm < 0.0f)      { *rt1 = 0.5f*(sm - rt); sgn1 = -1;
                          *rt2 = (acmx / *rt1)*acmn - (b / *rt1)*b; }
    else if (sm > 0.0f) { *rt1 = 0.5f*(sm + rt); sgn1 = 1;
                          *rt2 = (acmx / *rt1)*acmn - (b / *rt1)*b; }
    else                { *rt1 = 0.5f*rt; *rt2 = -0.5f*rt; sgn1 = 1; }
    float cs; int sgn2;
    if (df >= 0.0f) { cs = df + rt; sgn2 = 1; } else { cs = df - rt; sgn2 = -1; }
    float acs = fabsf(cs);
    float c1, s1;
    if (acs > ab) { float ct = -tb/cs; s1 = 1.0f/__fsqrt_rn(1.0f + ct*ct); c1 = ct*s1; }
    else {
        if (ab == 0.0f) { c1 = 1.0f; s1 = 0.0f; }
        else { float tn = -cs/tb; c1 = 1.0f/__fsqrt_rn(1.0f + tn*tn); s1 = tn*c1; }
    }
    if (sgn1 == sgn2) { float tn = c1; c1 = -s1; s1 = tn; }
    *cs1 = c1; *sn1 = s1;
}

__device__ void eigh3_smallest(float c00, float c01, float c02,
                               float c11, float c12, float c22, float nv[3])
{
#pragma clang fp contract(off)
    // ---- ssytrd('L') ----
    float d[4], e[3], z[4][4];
    float tau1, v2 = 0.0f;
    float e1, d2, d3, e2;
    float alpha = c01, x = c02;
    if (x == 0.0f) {
        tau1 = 0.0f; e1 = alpha;
        d2 = c11; d3 = c22; e2 = c12;
    } else {
        float beta = -f_sign(slapy2(alpha, fabsf(x)), alpha);
        tau1 = (beta - alpha) / beta;
        v2 = x / (alpha - beta);
        e1 = beta;
        float w1 = tau1*(c11 + c12*v2);
        float w2 = tau1*(c12 + c22*v2);
        float al = -0.5f*tau1*(w1 + w2*v2);
        w1 = w1 + al;
        w2 = w2 + al*v2;
        d2 = (c11 - w1) - w1;
        e2 = (c12 - v2*w1) - w2;
        d3 = (c22 - v2*w2) - w2*v2;
    }
    d[1] = c00; d[2] = d2; d[3] = d3;
    e[1] = e1;  e[2] = e2;
    z[1][1] = 1.0f; z[1][2] = 0.0f; z[1][3] = 0.0f;
    z[2][1] = 0.0f; z[3][1] = 0.0f;
    z[2][2] = 1.0f - tau1;
    float mtv = -tau1*v2;
    z[2][3] = mtv; z[3][2] = mtv;
    z[3][3] = 1.0f + mtv*v2;

    // ---- ssteqr('V', 3) ----
    const int n = 3, nm1 = 2;
    int l1 = 1, jtot = 0;
    const int nmaxit = 90;
    float cw[3], sw[3];
    int guard = 0;
    while (guard++ < 64) {
        if (l1 > n) break;
        if (l1 > 1) e[l1-1] = 0.0f;
        int m = n;
        if (l1 <= nm1) {
            for (int mi = l1; mi <= nm1; ++mi) {
                float tst = fabsf(e[mi]);
                if (tst == 0.0f) { m = mi; break; }
                if (tst <= (__fsqrt_rn(fabsf(d[mi]))*__fsqrt_rn(fabsf(d[mi+1])))*SEPS) {
                    e[mi] = 0.0f; m = mi; break;
                }
            }
        }
        int l = l1;
        int lsv = l, lend = m, lendsv = lend;
        l1 = m + 1;
        if (lend == l) continue;
        if (fabsf(d[lend]) < fabsf(d[l])) { lend = lsv; l = lendsv; }

        if (lend > l) {
            // QL
            while (true) {
                int m_ = lend;
                if (l != lend) {
                    for (int mi = l; mi <= lend-1; ++mi) {
                        float em = e[mi];
                        float tst = em*em;
                        if (tst <= (SEPS2*fabsf(d[mi]))*fabsf(d[mi+1]) + SSAFMIN) { m_ = mi; break; }
                    }
                }
                if (m_ < lend) e[m_] = 0.0f;
                float p = d[l];
                if (m_ == l) {
                    d[l] = p; l = l + 1;
                    if (l <= lend) continue; else break;
                }
                if (m_ == l + 1) {
                    float rt1, rt2, cc, ss;
                    slaev2_(d[l], e[l], d[l+1], &rt1, &rt2, &cc, &ss);
                    for (int i = 1; i <= 3; ++i) {
                        float tmp = z[i][l+1];
                        z[i][l+1] = cc*tmp - ss*z[i][l];
                        z[i][l]   = ss*tmp + cc*z[i][l];
                    }
                    d[l] = rt1; d[l+1] = rt2; e[l] = 0.0f;
                    l = l + 2;
                    if (l <= lend) continue; else break;
                }
                if (jtot == nmaxit) break;
                jtot++;
                float g = (d[l+1] - p) / (2.0f*e[l]);
                float r = slapy2(g, 1.0f);
                g = d[m_] - p + (e[l] / (g + f_sign(r, g)));
                float s = 1.0f, c = 1.0f;
                p = 0.0f;
                for (int i = m_-1; i >= l; --i) {
                    float f = s*e[i];
                    float b = c*e[i];
                    slartg_(g, f, &c, &s, &r);
                    if (i != m_-1) e[i+1] = r;
                    g = d[i+1] - p;
                    r = (d[i] - g)*s + (2.0f*c)*b;
                    p = s*r;
                    d[i+1] = g + p;
                    g = c*r - b;
                    cw[i] = c; sw[i] = -s;
                }
                for (int j = m_-1; j >= l; --j) {
                    float cc = cw[j], ss = sw[j];
                    for (int i = 1; i <= 3; ++i) {
                        float tmp = z[i][j+1];
                        z[i][j+1] = cc*tmp - ss*z[i][j];
                        z[i][j]   = ss*tmp + cc*z[i][j];
                    }
                }
                d[l] = d[l] - p;
                e[l] = g;
            }
        } else {
            // QR
            while (true) {
                int m_ = lend;
                if (l != lend) {
                    for (int mi = l; mi >= lend+1; --mi) {
                        float em = e[mi-1];
                        float tst = em*em;
                        if (tst <= (SEPS2*fabsf(d[mi]))*fabsf(d[mi-1]) + SSAFMIN) { m_ = mi; break; }
                    }
                }
                if (m_ > lend) e[m_-1] = 0.0f;
                float p = d[l];
                if (m_ == l) {
                    d[l] = p; l = l - 1;
                    if (l >= lend) continue; else break;
                }
                if (m_ == l - 1) {
                    float rt1, rt2, cc, ss;
                    slaev2_(d[l-1], e[l-1], d[l], &rt1, &rt2, &cc, &ss);
                    for (int i = 1; i <= 3; ++i) {
                        float tmp = z[i][l];
                        z[i][l]   = cc*tmp - ss*z[i][l-1];
                        z[i][l-1] = ss*tmp + cc*z[i][l-1];
                    }
                    d[l-1] = rt1; d[l] = rt2; e[l-1] = 0.0f;
                    l = l - 2;
                    if (l >= lend) continue; else break;
                }
                if (jtot == nmaxit) break;
                jtot++;
                float g = (d[l-1] - p) / (2.0f*e[l-1]);
                float r = slapy2(g, 1.0f);
                g = d[m_] - p + (e[l-1] / (g + f_sign(r, g)));
                float s = 1.0f, c = 1.0f;
                p = 0.0f;
                for (int i = m_; i <= l-1; ++i) {
                    float f = s*e[i];
                    float b = c*e[i];
                    slartg_(g, f, &c, &s, &r);
                    if (i != m_) e[i-1] = r;
                    g = d[i] - p;
                    r = (d[i+1] - g)*s + (2.0f*c)*b;
                    p = s*r;
                    d[i] = g + p;
                    g = c*r - b;
                    cw[i] = c; sw[i] = s;
                }
                for (int j = m_; j <= l-1; ++j) {
                    float cc = cw[j], ss = sw[j];
                    for (int i = 1; i <= 3; ++i) {
                        float tmp = z[i][j+1];
                        z[i][j+1] = cc*tmp - ss*z[i][j];
                        z[i][j]   = ss*tmp + cc*z[i][j];
                    }
                }
                d[l] = d[l] - p;
                e[l-1] = g;
            }
        }
    }
    for (int ii = 2; ii <= 3; ++ii) {
        int i = ii - 1, k = i;
        float p = d[i];
        for (int j = ii; j <= 3; ++j) if (d[j] < p) { k = j; p = d[j]; }
        if (k != i) {
            d[k] = d[i]; d[i] = p;
            for (int r2 = 1; r2 <= 3; ++r2) {
                float t = z[r2][i]; z[r2][i] = z[r2][k]; z[r2][k] = t;
            }
        }
    }
    nv[0] = z[1][1]; nv[1] = z[2][1]; nv[2] = z[3][1];
}

// Covariance of the sorted 10-neighborhood (same op order as rounds 2-18).
__device__ void cov_compute(const float4* __restrict__ cl,
                            const unsigned long long keys[KNN], float c[6])
{
#pragma clang fp contract(off)
    float px[KNN], py[KNN], pz[KNN];
    float sx = 0.f, sy = 0.f, sz = 0.f;
    #pragma unroll
    for (int s = 0; s < KNN; ++s) {
        int ni = (int)(unsigned)(keys[s] & 0xFFFFFFFFull);
        float4 np = cl[ni];
        px[s] = np.x; py[s] = np.y; pz[s] = np.z;
        sx = sx + px[s]; sy = sy + py[s]; sz = sz + pz[s];
    }
    float mx = sx / 10.0f, my = sy / 10.0f, mz = sz / 10.0f;
    float c00=0.f,c01=0.f,c02=0.f,c11=0.f,c12=0.f,c22=0.f;
    #pragma unroll
    for (int s = 0; s < KNN; ++s) {
        float dx = px[s]-mx, dy = py[s]-my, dz = pz[s]-mz;
        c00 = c00 + dx*dx; c01 = c01 + dx*dy; c02 = c02 + dx*dz;
        c11 = c11 + dy*dy; c12 = c12 + dy*dz; c22 = c22 + dz*dz;
    }
    c[0] = c00/10.0f; c[1] = c01/10.0f; c[2] = c02/10.0f;
    c[3] = c11/10.0f; c[4] = c12/10.0f; c[5] = c22/10.0f;
}

// ---------------------------------------------------------------------------
// Insert: gate = min(own 10th, quad bound). Dropping candidates >= the quad
// bound is exact: some lane already holds 10 strictly-better keys. In phases
// 2/3 qbK is ~0ull so the gate degenerates to the (exact) own 10th.
// ---------------------------------------------------------------------------
#define PROC(p) do { \
    float ddx = qx - (p).x, ddy = qy - (p).y, ddz = qz - (p).z; \
    float dd = fmaf(ddz, ddz, fmaf(ddy, ddy, ddx*ddx)); \
    unsigned long long key = \
        ((unsigned long long)__float_as_uint(dd) << 32) | \
        (unsigned)__float_as_int((p).w); \
    if (key < kgate) { \
        unsigned long long ck = key; \
        _Pragma("unroll") \
        for (int s = 0; s < KNN; ++s) { \
            unsigned long long ok2 = keys[s]; \
            bool sw = ok2 > ck; \
            keys[s] = sw ? ck : ok2; \
            ck      = sw ? ok2 : ck; \
        } \
        k9 = keys[KNN-1]; \
        kgate = (k9 < qbK) ? k9 : qbK; \
    } \
} while (0)

// R24 cooperative stride-4 segment walk: the QUAD jointly covers [bgn,end);
// lane sub takes elements bgn+sub, +4, +8, ... Perfect quad balance and the
// quad's 4 loads are one contiguous 64B chunk. Disjointness across lanes
// preserved -> per-lane exact reservoirs.
#define SEGPROC(bgn, end) do { \
    int _j = (bgn) + sub, _je = (end); \
    for (; _j + 4 < _je; _j += 8) { \
        float4 _p0 = cs[_j]; float4 _p1 = cs[_j+4]; \
        PROC(_p0); PROC(_p1); \
    } \
    if (_j < _je) { float4 _p0 = cs[_j]; PROC(_p0); } \
} while (0)

// quad-min of the four lanes' current 10th keys; low word forced to all-ones
// so ties on the distance bits still pass the gate (tie-exact).
#define QEXCH() do { \
    unsigned long long _o1 = __shfl_xor(k9, 1, 4); \
    unsigned long long _m1 = (_o1 < k9) ? _o1 : k9; \
    unsigned long long _o2 = __shfl_xor(_m1, 2, 4); \
    unsigned long long _qm = (_o2 < _m1) ? _o2 : _m1; \
    qbK = _qm | 0xFFFFFFFFull; \
    kgate = (k9 < qbK) ? k9 : qbK; \
} while (0)

// R24 quad EXTRACTION merge: 10 rounds; per round a 2-stage u64-min butterfly
// finds the global min of the 4 sorted lists, every lane records it, every
// lane whose head equals it shifts down (shared keys collapse -> natural
// dedupe). Exact top-10 of the union, ascending, IDENTICAL in all 4 lanes.
#define QMERGE() do { \
    unsigned long long fin[KNN]; \
    _Pragma("unroll") \
    for (int r = 0; r < KNN; ++r) { \
        unsigned long long m = keys[0]; \
        unsigned long long _o1 = __shfl_xor(m, 1, 4); m = (_o1 < m) ? _o1 : m; \
        unsigned long long _o2 = __shfl_xor(m, 2, 4); m = (_o2 < m) ? _o2 : m; \
        fin[r] = m; \
        bool own = (keys[0] == m); \
        _Pragma("unroll") \
        for (int t = 0; t < KNN-1; ++t) keys[t] = own ? keys[t+1] : keys[t]; \
        keys[KNN-1] = own ? 0xFFFFFFFFFFFFFFFFull : keys[KNN-1]; \
    } \
    _Pragma("unroll") \
    for (int s = 0; s < KNN; ++s) keys[s] = fin[s]; \
    k9 = keys[KNN-1]; \
} while (0)

// ---------------------------------------------------------------------------
// Kernel D (R28 = R25 + PHASE 3): grid 10-NN, FOUR lanes per query, 256-thr
// blocks, R23 5<->5 swizzle. Phases 1/2 unchanged (exact cube top-10, exact
// phase-2 skip, tight worstM pruning). NEW: quads still unresolved at radius
// 2H (~3.4% of queries — these were the overflow) walk the rho=3 shell (24
// contiguous rows + 50 isolated cells) with the same exact worst_m pruning,
// re-merge, and re-test at 3H. Effect: overflow count ~2240 -> ~1000 AND the
// remaining overflow records carry FULL, TIGHT bounds (10th within rho<=3),
// so brute's gate rejects ~all candidates (its 75-instr insert chain — the
// measured straggler cost — almost never fires). Exactness: pruned cells have
// mindist^2 > worst_m >= final 10th (10 strictly-better keys exist); inserts
// gated by own k9 (exact); QMERGE dedupes; (3H)^2 gap argument == (2H)^2 one.
// Bit-identical output.
// ---------------------------------------------------------------------------
__global__ __launch_bounds__(256) void knn_main_kernel(
    const float4* __restrict__ P4, const float4* __restrict__ S,
    const int2* __restrict__ combo, float4* __restrict__ Cov,
    int* __restrict__ ovf, unsigned long long* __restrict__ ovf_key,
    int* __restrict__ ovf_count)
{
    int b = blockIdx.x;                         // 0..1023
    int bb = ((b & 31) << 5) | (b >> 5);        // 5<->5 bit swap (bijective)
    int tidg = bb * 256 + threadIdx.x;          // 0..262143
    int qid  = tidg >> 2;                       // 0..65535
    int sub  = tidg & 3;
    int pair = qid >> 13;                       // 8 clouds
    int spos = qid & (NN - 1);                  // sorted position
    const float4* __restrict__ cl = P4 + (size_t)pair * NN;
    const float4* __restrict__ cs = S  + (size_t)pair * NN;
    const int2*   __restrict__ cb = combo + (size_t)pair * NCELLS;

    float4 q = cs[spos];
    float qx = q.x, qy = q.y, qz = q.z;
    int qi = __float_as_int(q.w);               // original index in cloud
    int qcx = cellc(qx), qcy = cellc(qy), qcz = cellc(qz);

    unsigned long long keys[KNN];
    #pragma unroll
    for (int s = 0; s < KNN; ++s) keys[s] = 0xFFFFFFFFFFFFFFFFull;
    unsigned long long k9    = 0xFFFFFFFFFFFFFFFFull;
    unsigned long long qbK   = 0xFFFFFFFFFFFFFFFFull;
    unsigned long long kgate = 0xFFFFFFFFFFFFFFFFull;

    // ---- phase 1: rho<=1 cube = 9 (z,y) rows, center-out order so gates
    // tighten early; QEXCH between rows shares the quad bound.
    int x0 = max(qcx - 1, 0), x1 = min(qcx + 1, G - 1);
    {
        const int DZ9[9] = { 0,  0,  0, -1,  1, -1, -1,  1,  1};
        const int DY9[9] = { 0,  1, -1,  0,  0, -1,  1, -1,  1};
        int rb[9], re[9];
        #pragma unroll
        for (int r = 0; r < 9; ++r) {
            int zz = qcz + DZ9[r], yy = qcy + DY9[r];
            rb[r] = 0; re[r] = 0;
            if ((unsigned)zz < G && (unsigned)yy < G) {
                int cbase = (zz*G + yy)*G;
                int2 a  = cb[cbase + x0];
                int2 b2 = cb[cbase + x1];
                rb[r] = a.x; re[r] = b2.x + b2.y;
            }
        }
        #pragma unroll
        for (int r = 0; r < 9; ++r) {
            SEGPROC(rb[r], re[r]);
            if (r == 0 || r == 2 || r == 4 || r == 6) QEXCH();
        }
    }

    // ---- quad extraction-merge -> exact cube top-10, identical in all lanes
    QMERGE();
    const unsigned long long k9M = k9;          // exact cube 10th (u64 key)
    float worstM = __uint_as_float((unsigned)(k9M >> 32)); // NaN if <10 found

    // ---- phase 2: rho=2 shell. Exterior of the cube is >= H from q, so
    // skip iff H^2 > worstM is EXACT (NaN-safe: NaN -> walk shell).
    bool skip = (H*H > worstM);                 // quad-uniform (worstM shared)

    qbK   = 0xFFFFFFFFFFFFFFFFull;              // phase-2 gate = own 10th
    kgate = k9;
    if (!skip) {
        int xs0 = max(qcx - 2, 0), xs1 = min(qcx + 2, G - 1);
        // 16 outer rows; box test redundant in all 4 lanes (same q -> same
        // result, quad-uniform branch), then cooperative stride-4 walk.
        const int SZ16[16] = {-2,-2,-2,-2,-2,  2, 2, 2, 2, 2, -1,-1, 0, 0, 1, 1};
        const int SY16[16] = {-2,-1, 0, 1, 2, -2,-1, 0, 1, 2, -2, 2,-2, 2,-2, 2};
        #pragma unroll
        for (int r = 0; r < 16; ++r) {
            int zz = qcz + SZ16[r], yy = qcy + SY16[r];
            if ((unsigned)zz < G && (unsigned)yy < G) {
                float loy = fmaf((float)yy, H, GRID_LO);
                float loz = fmaf((float)zz, H, GRID_LO);
                float py = fmaxf(0.0f, fmaxf(loy - qy, qy - (loy + H)));
                float pz = fmaxf(0.0f, fmaxf(loz - qz, qz - (loz + H)));
                float pyz = fmaf(pz, pz, py*py);
                if (!(pyz > worstM)) {
                    int cbase = (zz*G + yy)*G;
                    int2 a  = cb[cbase + xs0];
                    int2 b2 = cb[cbase + xs1];
                    SEGPROC(a.x, b2.x + b2.y);
                }
            }
        }
        // 18 isolated cells (|dz|<=1,|dy|<=1, dx=+/-2)
        const int CZ18[18] = {-1,-1,-1,-1,-1,-1,  0, 0, 0, 0, 0, 0,  1, 1, 1, 1, 1, 1};
        const int CY18[18] = {-1,-1, 0, 0, 1, 1, -1,-1, 0, 0, 1, 1, -1,-1, 0, 0, 1, 1};
        const int CX18[18] = {-2, 2,-2, 2,-2, 2, -2, 2,-2, 2,-2, 2, -2, 2,-2, 2,-2, 2};
        #pragma unroll
        for (int r = 0; r < 18; ++r) {
            int zz = qcz + CZ18[r], yy = qcy + CY18[r], xx = qcx + CX18[r];
            if ((unsigned)zz < G && (unsigned)yy < G && (unsigned)xx < G) {
                float lox = fmaf((float)xx, H, GRID_LO);
                float loy = fmaf((float)yy, H, GRID_LO);
                float loz = fmaf((float)zz, H, GRID_LO);
                float px = fmaxf(0.0f, fmaxf(lox - qx, qx - (lox + H)));
                float py = fmaxf(0.0f, fmaxf(loy - qy, qy - (loy + H)));
                float pz = fmaxf(0.0f, fmaxf(loz - qz, qz - (loz + H)));
                float m2 = fmaf(pz, pz, fmaf(py, py, px*px));
                if (!(m2 > worstM)) {
                    int2 a = cb[(zz*G + yy)*G + xx];
                    SEGPROC(a.x, a.x + a.y);
                }
            }
        }
    }

    // ---- phase-2 final merge (only if some lane inserted; quad-uniform)
    if (!skip) {
        int ch = (k9 != k9M) ? 1 : 0;
        ch |= __shfl_xor(ch, 1, 4);
        ch |= __shfl_xor(ch, 2, 4);
        if (ch) QMERGE();
    }
    float worst_m = __uint_as_float((unsigned)(k9 >> 32));

    // resolved at 2H iff cells beyond rho<=2 (gap >= 2H) cannot contribute
    float bf = (float)RCAP * H;
    bool resolved = (bf*bf > worst_m);          // strict; NaN (unfilled) -> false

    // ---- phase 3 (R28): rho=3 shell for the ~3.4% still-unresolved quads.
    // Branch is quad-uniform (worst_m shared after merge) -> shfls safe.
    if (!resolved) {
        const unsigned long long k9P2 = k9;     // state after phase-2 merge
        qbK   = 0xFFFFFFFFFFFFFFFFull;
        kgate = k9;
        int xt0 = max(qcx - 3, 0), xt1 = min(qcx + 3, G - 1);
        // 24 outer rows (|dz|==3 or |dy|==3), contiguous x in [qcx-3,qcx+3]
        const int SZ24[24] = {-3,-3,-3,-3,-3,-3,-3,  3, 3, 3, 3, 3, 3, 3,
                              -2,-2,-1,-1, 0, 0, 1, 1, 2, 2};
        const int SY24[24] = {-3,-2,-1, 0, 1, 2, 3, -3,-2,-1, 0, 1, 2, 3,
                              -3, 3,-3, 3,-3, 3,-3, 3,-3, 3};
        #pragma unroll
        for (int r = 0; r < 24; ++r) {
            int zz = qcz + SZ24[r], yy = qcy + SY24[r];
            if ((unsigned)zz < G && (unsigned)yy < G) {
                float loy = fmaf((float)yy, H, GRID_LO);
                float loz = fmaf((float)zz, H, GRID_LO);
                float py = fmaxf(0.0f, fmaxf(loy - qy, qy - (loy + H)));
                float pz = fmaxf(0.0f, fmaxf(loz - qz, qz - (loz + H)));
                float pyz = fmaf(pz, pz, py*py);
                if (!(pyz > worst_m)) {
                    int cbase = (zz*G + yy)*G;
                    int2 a  = cb[cbase + xt0];
                    int2 b2 = cb[cbase + xt1];
                    SEGPROC(a.x, b2.x + b2.y);
                }
            }
        }
        // 50 isolated cells: |dz|<=2, |dy|<=2, dx = +/-3
        #pragma unroll 1
        for (int r = 0; r < 50; ++r) {
            int dz = (r / 10) - 2;
            int dy = ((r >> 1) % 5) - 2;
            int dx = (r & 1) ? 3 : -3;
            int zz = qcz + dz, yy = qcy + dy, xx = qcx + dx;
            if ((unsigned)zz < G && (unsigned)yy < G && (unsigned)xx < G) {
                float lox = fmaf((float)xx, H, GRID_LO);
                float loy = fmaf((float)yy, H, GRID_LO);
                float loz = fmaf((float)zz, H, GRID_LO);
                float px = fmaxf(0.0f, fmaxf(lox - qx, qx - (lox + H)));
                float py = fmaxf(0.0f, fmaxf(loy - qy, qy - (loy + H)));
                float pz = fmaxf(0.0f, fmaxf(loz - qz, qz - (loz + H)));
                float m2 = fmaf(pz, pz, fmaf(py, py, px*px));
                if (!(m2 > worst_m)) {
                    int2 a = cb[(zz*G + yy)*G + xx];
                    SEGPROC(a.x, a.x + a.y);
                }
            }
        }
        int ch = (k9 != k9P2) ? 1 : 0;
        ch |= __shfl_xor(ch, 1, 4);
        ch |= __shfl_xor(ch, 2, 4);
        if (ch) QMERGE();
        worst_m = __uint_as_float((unsigned)(k9 >> 32));
        float bf3 = 3.0f * H;
        resolved = (bf3*bf3 > worst_m);         // cells beyond rho<=3: gap>=3H
    }

    if (resolved && sub == 0) {
        float c[6];
        cov_compute(cl, keys, c);               // sub==0 only: 1/4 gather loads
        size_t o = ((size_t)pair*NN + qi)*2;
        Cov[o]   = make_float4(c[0], c[1], c[2], c[3]);
        Cov[o+1] = make_float4(c[4], c[5], 0.0f, 0.0f);
    } else if (!resolved && sub == 0) {
        int pos = atomicAdd(ovf_count, 1);
        ovf[pos] = (pair << 13) | qi;
        ovf_key[pos] = k9;      // exact 10th over examined set (now rho<=3):
    }                           // tight upper bound on the true 10th key
}

// ---------------------------------------------------------------------------
// Kernel D2 (R28 = R25 config): brute-force overflow, ONE BLOCK (256 thr =
// 4 waves) per query, 2048 blocks (>= new ~1000 count -> one residency
// round). With phase-3 bounds nearly all candidates fail the dd-gate, so the
// insert chain (the measured straggler cost) almost never fires. Merge path:
// per-wave 10-round extraction, lane 0 posts to LDS, thread 0 4-list
// head-pointer merge. Exact top-10 of the union ascending => bit-identical.
// ---------------------------------------------------------------------------
#define BRUTE_BLOCKS 2048
__global__ __launch_bounds__(256) void brute_kernel(
    const float4* __restrict__ P4, const int* __restrict__ ovf,
    const unsigned long long* __restrict__ ovf_key,
    const int* __restrict__ ovf_count, float4* __restrict__ Cov)
{
    __shared__ unsigned long long wl[4][KNN];
    int tid = threadIdx.x;
    int lane = tid & 63;
    int wid = tid >> 6;
    int count = *ovf_count;

    for (int oi = blockIdx.x; oi < count; oi += BRUTE_BLOCKS) {
        int rec = ovf[oi];
        unsigned long long bound = ovf_key[oi];
        float bound_d = __uint_as_float((unsigned)(bound >> 32)); // NaN if unfilled
        int pair = rec >> 13;
        int qi = rec & (NN - 1);
        const float4* __restrict__ cl = P4 + (size_t)pair * NN;
        float4 q = cl[qi];
        float qx = q.x, qy = q.y, qz = q.z;

        unsigned long long keys[KNN];
        #pragma unroll
        for (int s = 0; s < KNN; ++s) keys[s] = 0xFFFFFFFFFFFFFFFFull;
        unsigned long long k9 = keys[KNN-1];

        // per-thread scan of a disjoint 1/256 slice (32 candidates), bound-
        // gated; ties at dd==bound_d pass (exact). Coalesced cl[i*256+tid].
#define BPROC(p, jj) do { \
        float ddx = qx - (p).x, ddy = qy - (p).y, ddz = qz - (p).z; \
        float dd = fmaf(ddz, ddz, fmaf(ddy, ddy, ddx*ddx)); \
        if (!(dd > bound_d)) { \
            unsigned long long key = \
                ((unsigned long long)__float_as_uint(dd) << 32) | (unsigned)(jj); \
            if (key < k9) { \
                unsigned long long ck = key; \
                _Pragma("unroll") \
                for (int s = 0; s < KNN; ++s) { \
                    unsigned long long ok2 = keys[s]; \
                    bool sw = ok2 > ck; \
                    keys[s] = sw ? ck : ok2; \
                    ck      = sw ? ok2 : ck; \
                } \
                k9 = keys[KNN-1]; \
            } \
        } \
    } while (0)
        #pragma unroll 1
        for (int i = 0; i < 32; i += 4) {       // 8 iters, 4 loads in flight
            float4 p0 = cl[(i+0)*256 + tid];
            float4 p1 = cl[(i+1)*256 + tid];
            float4 p2 = cl[(i+2)*256 + tid];
            float4 p3 = cl[(i+3)*256 + tid];
            BPROC(p0, (i+0)*256 + tid);
            BPROC(p1, (i+1)*256 + tid);
            BPROC(p2, (i+2)*256 + tid);
            BPROC(p3, (i+3)*256 + tid);
        }
#undef BPROC

        // per-wave 10-round extraction merge: exact wave top-10, ascending,
        // identical in all 64 lanes (sentinel ties shift all owners — safe).
        unsigned long long fin[KNN];
        #pragma unroll
        for (int r = 0; r < KNN; ++r) {
            unsigned long long m = keys[0];
            #pragma unroll
            for (int off = 1; off < 64; off <<= 1) {
                unsigned long long o = __shfl_xor(m, off);
                m = (o < m) ? o : m;
            }
            fin[r] = m;
            if (keys[0] == m) {
                #pragma unroll
                for (int t = 0; t < KNN-1; ++t) keys[t] = keys[t+1];
                keys[KNN-1] = 0xFFFFFFFFFFFFFFFFull;
            }
        }

        if (lane == 0) {
            #pragma unroll
            for (int s = 0; s < KNN; ++s) wl[wid][s] = fin[s];
        }
        __syncthreads();
        if (tid == 0) {
            // 4-list head-pointer extraction merge (lists sorted ascending).
            // Real keys unique -> exactly one list advances; equal sentinels
            // advance together (reads precede advances; idx <= round <= 9).
            int i0 = 0, i1 = 0, i2 = 0, i3 = 0;
            unsigned long long outk[KNN];
            #pragma unroll
            for (int r = 0; r < KNN; ++r) {
                unsigned long long h0 = wl[0][i0], h1 = wl[1][i1];
                unsigned long long h2 = wl[2][i2], h3 = wl[3][i3];
                unsigned long long m01 = (h0 < h1) ? h0 : h1;
                unsigned long long m23 = (h2 < h3) ? h2 : h3;
                unsigned long long m   = (m01 < m23) ? m01 : m23;
                outk[r] = m;
                i0 += (h0 == m); i1 += (h1 == m);
                i2 += (h2 == m); i3 += (h3 == m);
            }
            float c[6];
            cov_compute(cl, outk, c);
            size_t o = ((size_t)pair*NN + qi)*2;
            Cov[o]   = make_float4(c[0], c[1], c[2], c[3]);
            Cov[o+1] = make_float4(c[4], c[5], 0.0f, 0.0f);
        }
        __syncthreads();                        // protect wl for next query
    }
}

// ---------------------------------------------------------------------------
// Kernel E (R19): fused eigh + loss, ONE eigh per thread over 2*BN threads.
// Thread 2k handles gt[k], thread 2k+1 handles pred[k]; normals exchanged
// in-wave via shfl_xor(1); even lanes compute 1-cos; block reduce; atomic.
// Identical eigh inputs -> bit-identical normals (summation grouping only).
// ---------------------------------------------------------------------------
__global__ __launch_bounds__(256) void eigh_loss_kernel(
    const float4* __restrict__ Cov, float* __restrict__ accum,
    unsigned* __restrict__ counter, float* __restrict__ out)
{
    int tid = threadIdx.x;
    int t = blockIdx.x * 256 + tid;            // 0..2*BN-1
    int k = t >> 1;                            // pair index 0..BN-1
    int cld = t & 1;                           // 0 = gt, 1 = pred
    size_t ci = ((size_t)(cld ? BN + k : k)) * 2;
    float4 a0 = Cov[ci], a1 = Cov[ci + 1];
    float n[3];
    eigh3_smallest(a0.x, a0.y, a0.z, a0.w, a1.x, a1.y, n);

    // exchange with partner lane (2k <-> 2k+1 always share a wave)
    float ox = __shfl_xor(n[0], 1);
    float oy = __shfl_xor(n[1], 1);
    float oz = __shfl_xor(n[2], 1);

    float v = 0.0f;
    if (cld == 0) {
        float gx=n[0], gy=n[1], gz=n[2];
        float hx=ox,  hy=oy,  hz=oz;
        float dot = fmaf(gx,hx,fmaf(gy,hy,gz*hz));
        float ng  = sqrtf(fmaf(gx,gx,fmaf(gy,gy,gz*gz)));
        float nh  = sqrtf(fmaf(hx,hx,fmaf(hy,hy,hz*hz)));
        float den = fmaxf(ng*nh, 1e-8f);
        v = 1.0f - dot/den;
    }

    __shared__ float red[256];
    red[tid] = v;                              // odd lanes contribute 0
    __syncthreads();
    for (int s = 128; s > 0; s >>= 1) {
        if (tid < s) red[tid] += red[tid+s];
        __syncthreads();
    }
    if (tid == 0) {
        atomicAdd(accum, red[0]);
        __threadfence();
        unsigned old = atomicAdd(counter, 1u);
        if (old == (unsigned)(2*BN/256 - 1)) {
            float tot = atomicAdd(accum, 0.0f);
            out[0] = tot * (1.0f/(float)BN);
        }
    }
}

// ---------------------------------------------------------------------------
extern "C" void kernel_launch(void* const* d_in, const int* in_sizes, int n_in,
                              void* d_out, int out_size, void* d_ws, size_t ws_size,
                              hipStream_t stream)
{
    (void)in_sizes; (void)n_in; (void)out_size; (void)ws_size;
    const float*    gt   = (const float*)d_in[0];
    const float*    pred = (const float*)d_in[1];
    const unsigned* idxw = (const unsigned*)d_in[2];
    float* out = (float*)d_out;

    char* w = (char*)d_ws;
    float4* P4   = (float4*)w;                         w += (size_t)2*BN*16;   // 1 MB
    float4* S    = (float4*)w;                         w += (size_t)2*BN*16;   // 1 MB
    int*    hist = (int*)w;                            w += (size_t)8*NCELLS*4;   // 1 MB
    int2*   combo = (int2*)w;                          w += (size_t)8*NCELLS*8;   // 2 MB
    float4* Cov  = (float4*)w;                         w += (size_t)2*BN*32;   // 2 MB
    float*  accum = (float*)w;                         w += 16;
    unsigned* counter = (unsigned*)(accum + 1);
    int*    ovf_count = (int*)(accum + 2);
    int*    ovf  = (int*)w;                            w += (size_t)2*BN*4;    // 0.25 MB
    unsigned long long* ovf_key = (unsigned long long*)w;  w += (size_t)2*BN*8; // 0.5 MB

    hipMemsetAsync(hist, 0, (size_t)8*NCELLS*4, stream);
    hipLaunchKernelGGL(prep_kernel,    dim3(2*BN/256), dim3(256),  0, stream,
                       gt, pred, idxw, P4, hist, accum, counter, ovf_count);
    hipLaunchKernelGGL(scan_kernel,    dim3(8),        dim3(1024), 0, stream,
                       hist, combo);
    hipLaunchKernelGGL(scatter_kernel, dim3(2*BN/256), dim3(256),  0, stream,
                       P4, hist, combo, S);
    hipLaunchKernelGGL(knn_main_kernel, dim3(2*BN*4/256), dim3(256), 0, stream,
                       P4, S, combo, Cov, ovf, ovf_key, ovf_count);
    hipLaunchKernelGGL(brute_kernel,   dim3(BRUTE_BLOCKS), dim3(256), 0, stream,
                       P4, ovf, ovf_key, ovf_count, Cov);
    hipLaunchKernelGGL(eigh_loss_kernel, dim3(2*BN/256), dim3(256), 0, stream,
                       Cov, accum, counter, out);
}

// Round 10
// 233.784 us; speedup vs baseline: 1.1602x; 1.0103x over previous
//
#include <hip/hip_runtime.h>
#include <math.h>

#define BB   4
#define NN   8192
#define BN   (BB*NN)       // 32768 points per cloud-set; 8 clouds of 8192 total
#define KNN  10
#define G    32            // grid cells per dim
#define NCELLS (G*G*G)     // 32768 cells per cloud
#define GRID_LO (-5.0f)
#define H    0.3125f       // 10/32
#define INV_H 3.2f
#define RCAP 2             // rho<=2 resolution for the fast path; phase 3 -> 3

#define SEPS    5.9604645e-8f        // slamch('E') = 2^-24
#define SEPS2   (SEPS*SEPS)
#define SSAFMIN 1.1754944e-38f

__device__ __forceinline__ int cellc(float v) {
    int c = (int)floorf((v - GRID_LO) * INV_H);
    return min(G - 1, max(0, c));
}

// ---------------------------------------------------------------------------
// Kernel A: build P4[8][8192] = (x,y,z, bitcast orig-idx); clouds 0-3 = gt
// batches, 4-7 = pred[idx12] batches. Histogram cells + zero accumulators.
// ---------------------------------------------------------------------------
__global__ __launch_bounds__(256) void prep_kernel(
    const float* __restrict__ gt, const float* __restrict__ pred,
    const unsigned* __restrict__ idxw, float4* __restrict__ P4,
    int* __restrict__ hist, float* __restrict__ accum,
    unsigned* __restrict__ counter, int* __restrict__ ovf_count)
{
    __shared__ int s_is32;
    int tid = threadIdx.x;
    if (tid == 0) s_is32 = 0;
    __syncthreads();
    if (idxw[2*tid + 1] != 0u) s_is32 = 1;   // int64 => all high words 0
    __syncthreads();
    bool is64 = (s_is32 == 0);

    if (blockIdx.x == 0 && tid == 0) {
        *accum = 0.0f; *counter = 0u; *ovf_count = 0;
    }

    int point = blockIdx.x * 256 + tid;        // 0 .. 2*BN-1
    int pair = point >> 13;                    // 0..7
    int r    = point & (NN - 1);               // idx within cloud
    float x, y, z;
    if (point < BN) {
        const float* s = gt + (size_t)point*3;
        x = s[0]; y = s[1]; z = s[2];
    } else {
        int rr = point - BN;
        int b = rr >> 13;
        unsigned idx = is64 ? idxw[2*(size_t)rr] : idxw[rr];
        const float* s = pred + ((size_t)b*NN + idx)*3;
        x = s[0]; y = s[1]; z = s[2];
    }
    P4[point] = make_float4(x, y, z, __int_as_float(r));
    int cell = (cellc(z)*G + cellc(y))*G + cellc(x);
    atomicAdd(&hist[(size_t)pair*NCELLS + cell], 1);
}

// ---------------------------------------------------------------------------
// Kernel B: per-cloud exclusive scan -> combo[c] = int2(start, count).
// ---------------------------------------------------------------------------
__global__ __launch_bounds__(1024) void scan_kernel(
    const int* __restrict__ hist, int2* __restrict__ combo)
{
    int cloud = blockIdx.x;
    int tid = threadIdx.x;
    int lane = tid & 63, wid = tid >> 6;
    const int* h = hist + (size_t)cloud * NCELLS;
    int2* cb = combo + (size_t)cloud * NCELLS;

    int loc[32];
    int base = tid * 32;
    const int4* h4 = (const int4*)(h + base);
    int sum = 0;
    #pragma unroll
    for (int i = 0; i < 8; ++i) {
        int4 a = h4[i];
        loc[4*i+0] = a.x; loc[4*i+1] = a.y; loc[4*i+2] = a.z; loc[4*i+3] = a.w;
        sum += a.x + a.y + a.z + a.w;
    }
    // inclusive wave scan of sums
    int v = sum;
    #pragma unroll
    for (int off = 1; off < 64; off <<= 1) {
        int o = __shfl_up(v, off, 64);
        if (lane >= off) v += o;
    }
    __shared__ int ws[16], wsx[16];
    if (lane == 63) ws[wid] = v;
    __syncthreads();
    if (tid < 16) {
        int acc = 0;
        for (int i = 0; i < tid; ++i) acc += ws[i];
        wsx[tid] = acc;
    }
    __syncthreads();
    int run = (v - sum) + wsx[wid];            // exclusive prefix for this thread

    int4* cb4 = (int4*)(cb + base);            // 2 cells per int4 store
    #pragma unroll
    for (int i = 0; i < 16; ++i) {
        int4 o;
        o.x = run; o.y = loc[2*i];     run += loc[2*i];
        o.z = run; o.w = loc[2*i+1];   run += loc[2*i+1];
        cb4[i] = o;
    }
}

// ---------------------------------------------------------------------------
// Kernel C: scatter points into cell-sorted S.
// ---------------------------------------------------------------------------
__global__ __launch_bounds__(256) void scatter_kernel(
    const float4* __restrict__ P4, int* __restrict__ hist,
    const int2* __restrict__ combo, float4* __restrict__ S)
{
    int point = blockIdx.x * 256 + threadIdx.x;
    float4 p = P4[point];
    int pair = point >> 13;
    int cell = (cellc(p.z)*G + cellc(p.y))*G + cellc(p.x);
    int old = atomicSub(&hist[(size_t)pair*NCELLS + cell], 1);
    int pos = combo[(size_t)pair*NCELLS + cell].x + old - 1;
    S[(size_t)pair*NN + pos] = p;
}

// ---------------------------------------------------------------------------
// LAPACK ssyevd 3x3 path: ssytrd('L') + sorgtr + ssteqr('V'). Sign-faithful.
// (verified absmax 0.0 in rounds 2-18 — do not touch)
// ---------------------------------------------------------------------------
__device__ __forceinline__ float f_sign(float a, float b) {
    return copysignf(a, b);
}
__device__ __forceinline__ float slapy2(float x, float y) {
#pragma clang fp contract(off)
    float xa = fabsf(x), ya = fabsf(y);
    float w = fmaxf(xa, ya), z = fminf(xa, ya);
    if (z == 0.0f) return w;
    float t = z / w;
    return w * __fsqrt_rn(1.0f + t*t);
}
__device__ __forceinline__ void slartg_(float f, float g, float* cs, float* sn, float* r) {
#pragma clang fp contract(off)
    if (g == 0.0f)      { *cs = 1.0f; *sn = 0.0f; *r = f; }
    else if (f == 0.0f) { *cs = 0.0f; *sn = f_sign(1.0f, g); *r = fabsf(g); }
    else {
        float f1 = fabsf(f);
        float d = __fsqrt_rn(f*f + g*g);
        float p = 1.0f / d;
        *cs = f1 * p;
        *sn = g * f_sign(p, f);
        *r  = f_sign(d, f);
    }
}
__device__ void slaev2_(float a, float b, float c,
                        float* rt1, float* rt2, float* cs1, float* sn1) {
#pragma clang fp contract(off)
    float sm = a + c, df = a - c;
    float adf = fabsf(df);
    float tb = b + b;
    float ab = fabsf(tb);
    float acmx, acmn;
    if (fabsf(a) > fabsf(c)) { acmx = a; acmn = c; } else { acmx = c; acmn = a; }
    float rt;
    if (adf > ab)      { float t = ab/adf; rt = adf*__fsqrt_rn(1.0f + t*t); }
    else if (adf < ab) { float t = adf/ab; rt = ab*__fsqrt_rn(1.0f + t*t); }
    else               { rt = ab*__fsqrt_rn(2.0f); }
    int sgn1;
    if (sm < 0.0f)      { *rt1 = 0.5f*(sm - rt); sgn1 = -1;
                          *rt2 = (acmx / *rt1)*acmn - (b / *rt1)*b; }
    else if (sm > 0.0f) { *rt1 = 0.5f*(sm + rt); sgn1 = 1;
                          *rt2 = (acmx / *rt1)*acmn - (b / *rt1)*b; }
    else                { *rt1 = 0.5f*rt; *rt2 = -0.5f*rt; sgn1 = 1; }
    float cs; int sgn2;
    if (df >= 0.0f) { cs = df + rt; sgn2 = 1; } else { cs = df - rt; sgn2 = -1; }
    float acs = fabsf(cs);
    float c1, s1;
    if (acs > ab) { float ct = -tb/cs; s1 = 1.0f/__fsqrt_rn(1.0f + ct*ct); c1 = ct*s1; }
    else {
        if (ab == 0.0f) { c1 = 1.0f; s1 = 0.0f; }
        else { float tn = -cs/tb; c1 = 1.0f/__fsqrt_rn(1.0f + tn*tn); s1 = tn*c1; }
    }
    if (sgn1 == sgn2) { float tn = c1; c1 = -s1; s1 = tn; }
    *cs1 = c1; *sn1 = s1;
}

__device__ void eigh3_smallest(float c00, float c01, float c02,
                               float c11, float c12, float c22, float nv[3])
{
#pragma clang fp contract(off)
    // ---- ssytrd('L') ----
    float d[4], e[3], z[4][4];
    float tau1, v2 = 0.0f;
    float e1, d2, d3, e2;
    float alpha = c01, x = c02;
    if (x == 0.0f) {
        tau1 = 0.0f; e1 = alpha;
        d2 = c11; d3 = c22; e2 = c12;
    } else {
        float beta = -f_sign(slapy2(alpha, fabsf(x)), alpha);
        tau1 = (beta - alpha) / beta;
        v2 = x / (alpha - beta);
        e1 = beta;
        float w1 = tau1*(c11 + c12*v2);
        float w2 = tau1*(c12 + c22*v2);
        float al = -0.5f*tau1*(w1 + w2*v2);
        w1 = w1 + al;
        w2 = w2 + al*v2;
        d2 = (c11 - w1) - w1;
        e2 = (c12 - v2*w1) - w2;
        d3 = (c22 - v2*w2) - w2*v2;
    }
    d[1] = c00; d[2] = d2; d[3] = d3;
    e[1] = e1;  e[2] = e2;
    z[1][1] = 1.0f; z[1][2] = 0.0f; z[1][3] = 0.0f;
    z[2][1] = 0.0f; z[3][1] = 0.0f;
    z[2][2] = 1.0f - tau1;
    float mtv = -tau1*v2;
    z[2][3] = mtv; z[3][2] = mtv;
    z[3][3] = 1.0f + mtv*v2;

    // ---- ssteqr('V', 3) ----
    const int n = 3, nm1 = 2;
    int l1 = 1, jtot = 0;
    const int nmaxit = 90;
    float cw[3], sw[3];
    int guard = 0;
    while (guard++ < 64) {
        if (l1 > n) break;
        if (l1 > 1) e[l1-1] = 0.0f;
        int m = n;
        if (l1 <= nm1) {
            for (int mi = l1; mi <= nm1; ++mi) {
                float tst = fabsf(e[mi]);
                if (tst == 0.0f) { m = mi; break; }
                if (tst <= (__fsqrt_rn(fabsf(d[mi]))*__fsqrt_rn(fabsf(d[mi+1])))*SEPS) {
                    e[mi] = 0.0f; m = mi; break;
                }
            }
        }
        int l = l1;
        int lsv = l, lend = m, lendsv = lend;
        l1 = m + 1;
        if (lend == l) continue;
        if (fabsf(d[lend]) < fabsf(d[l])) { lend = lsv; l = lendsv; }

        if (lend > l) {
            // QL
            while (true) {
                int m_ = lend;
                if (l != lend) {
                    for (int mi = l; mi <= lend-1; ++mi) {
                        float em = e[mi];
                        float tst = em*em;
                        if (tst <= (SEPS2*fabsf(d[mi]))*fabsf(d[mi+1]) + SSAFMIN) { m_ = mi; break; }
                    }
                }
                if (m_ < lend) e[m_] = 0.0f;
                float p = d[l];
                if (m_ == l) {
                    d[l] = p; l = l + 1;
                    if (l <= lend) continue; else break;
                }
                if (m_ == l + 1) {
                    float rt1, rt2, cc, ss;
                    slaev2_(d[l], e[l], d[l+1], &rt1, &rt2, &cc, &ss);
                    for (int i = 1; i <= 3; ++i) {
                        float tmp = z[i][l+1];
                        z[i][l+1] = cc*tmp - ss*z[i][l];
                        z[i][l]   = ss*tmp + cc*z[i][l];
                    }
                    d[l] = rt1; d[l+1] = rt2; e[l] = 0.0f;
                    l = l + 2;
                    if (l <= lend) continue; else break;
                }
                if (jtot == nmaxit) break;
                jtot++;
                float g = (d[l+1] - p) / (2.0f*e[l]);
                float r = slapy2(g, 1.0f);
                g = d[m_] - p + (e[l] / (g + f_sign(r, g)));
                float s = 1.0f, c = 1.0f;
                p = 0.0f;
                for (int i = m_-1; i >= l; --i) {
                    float f = s*e[i];
                    float b = c*e[i];
                    slartg_(g, f, &c, &s, &r);
                    if (i != m_-1) e[i+1] = r;
                    g = d[i+1] - p;
                    r = (d[i] - g)*s + (2.0f*c)*b;
                    p = s*r;
                    d[i+1] = g + p;
                    g = c*r - b;
                    cw[i] = c; sw[i] = -s;
                }
                for (int j = m_-1; j >= l; --j) {
                    float cc = cw[j], ss = sw[j];
                    for (int i = 1; i <= 3; ++i) {
                        float tmp = z[i][j+1];
                        z[i][j+1] = cc*tmp - ss*z[i][j];
                        z[i][j]   = ss*tmp + cc*z[i][j];
                    }
                }
                d[l] = d[l] - p;
                e[l] = g;
            }
        } else {
            // QR
            while (true) {
                int m_ = lend;
                if (l != lend) {
                    for (int mi = l; mi >= lend+1; --mi) {
                        float em = e[mi-1];
                        float tst = em*em;
                        if (tst <= (SEPS2*fabsf(d[mi]))*fabsf(d[mi-1]) + SSAFMIN) { m_ = mi; break; }
                    }
                }
                if (m_ > lend) e[m_-1] = 0.0f;
                float p = d[l];
                if (m_ == l) {
                    d[l] = p; l = l - 1;
                    if (l >= lend) continue; else break;
                }
                if (m_ == l - 1) {
                    float rt1, rt2, cc, ss;
                    slaev2_(d[l-1], e[l-1], d[l], &rt1, &rt2, &cc, &ss);
                    for (int i = 1; i <= 3; ++i) {
                        float tmp = z[i][l];
                        z[i][l]   = cc*tmp - ss*z[i][l-1];
                        z[i][l-1] = ss*tmp + cc*z[i][l-1];
                    }
                    d[l-1] = rt1; d[l] = rt2; e[l-1] = 0.0f;
                    l = l - 2;
                    if (l >= lend) continue; else break;
                }
                if (jtot == nmaxit) break;
                jtot++;
                float g = (d[l-1] - p) / (2.0f*e[l-1]);
                float r = slapy2(g, 1.0f);
                g = d[m_] - p + (e[l-1] / (g + f_sign(r, g)));
                float s = 1.0f, c = 1.0f;
                p = 0.0f;
                for (int i = m_; i <= l-1; ++i) {
                    float f = s*e[i];
                    float b = c*e[i];
                    slartg_(g, f, &c, &s, &r);
                    if (i != m_) e[i-1] = r;
                    g = d[i] - p;
                    r = (d[i+1] - g)*s + (2.0f*c)*b;
                    p = s*r;
                    d[i] = g + p;
                    g = c*r - b;
                    cw[i] = c; sw[i] = s;
                }
                for (int j = m_; j <= l-1; ++j) {
                    float cc = cw[j], ss = sw[j];
                    for (int i = 1; i <= 3; ++i) {
                        float tmp = z[i][j+1];
                        z[i][j+1] = cc*tmp - ss*z[i][j];
                        z[i][j]   = ss*tmp + cc*z[i][j];
                    }
                }
                d[l] = d[l] - p;
                e[l-1] = g;
            }
        }
    }
    for (int ii = 2; ii <= 3; ++ii) {
        int i = ii - 1, k = i;
        float p = d[i];
        for (int j = ii; j <= 3; ++j) if (d[j] < p) { k = j; p = d[j]; }
        if (k != i) {
            d[k] = d[i]; d[i] = p;
            for (int r2 = 1; r2 <= 3; ++r2) {
                float t = z[r2][i]; z[r2][i] = z[r2][k]; z[r2][k] = t;
            }
        }
    }
    nv[0] = z[1][1]; nv[1] = z[2][1]; nv[2] = z[3][1];
}

// Covariance of the sorted 10-neighborhood (same op order as rounds 2-18).
__device__ void cov_compute(const float4* __restrict__ cl,
                            const unsigned long long keys[KNN], float c[6])
{
#pragma clang fp contract(off)
    float px[KNN], py[KNN], pz[KNN];
    float sx = 0.f, sy = 0.f, sz = 0.f;
    #pragma unroll
    for (int s = 0; s < KNN; ++s) {
        int ni = (int)(unsigned)(keys[s] & 0xFFFFFFFFull);
        float4 np = cl[ni];
        px[s] = np.x; py[s] = np.y; pz[s] = np.z;
        sx = sx + px[s]; sy = sy + py[s]; sz = sz + pz[s];
    }
    float mx = sx / 10.0f, my = sy / 10.0f, mz = sz / 10.0f;
    float c00=0.f,c01=0.f,c02=0.f,c11=0.f,c12=0.f,c22=0.f;
    #pragma unroll
    for (int s = 0; s < KNN; ++s) {
        float dx = px[s]-mx, dy = py[s]-my, dz = pz[s]-mz;
        c00 = c00 + dx*dx; c01 = c01 + dx*dy; c02 = c02 + dx*dz;
        c11 = c11 + dy*dy; c12 = c12 + dy*dz; c22 = c22 + dz*dz;
    }
    c[0] = c00/10.0f; c[1] = c01/10.0f; c[2] = c02/10.0f;
    c[3] = c11/10.0f; c[4] = c12/10.0f; c[5] = c22/10.0f;
}

// ---------------------------------------------------------------------------
// Insert: gate = min(own 10th, quad bound). Dropping candidates >= the quad
// bound is exact: some lane already holds 10 strictly-better keys. In phases
// 2/3 qbK is ~0ull so the gate degenerates to the (exact) own 10th.
// ---------------------------------------------------------------------------
#define PROC(p) do { \
    float ddx = qx - (p).x, ddy = qy - (p).y, ddz = qz - (p).z; \
    float dd = fmaf(ddz, ddz, fmaf(ddy, ddy, ddx*ddx)); \
    unsigned long long key = \
        ((unsigned long long)__float_as_uint(dd) << 32) | \
        (unsigned)__float_as_int((p).w); \
    if (key < kgate) { \
        unsigned long long ck = key; \
        _Pragma("unroll") \
        for (int s = 0; s < KNN; ++s) { \
            unsigned long long ok2 = keys[s]; \
            bool sw = ok2 > ck; \
            keys[s] = sw ? ck : ok2; \
            ck      = sw ? ok2 : ck; \
        } \
        k9 = keys[KNN-1]; \
        kgate = (k9 < qbK) ? k9 : qbK; \
    } \
} while (0)

// R24 cooperative stride-4 segment walk: the QUAD jointly covers [bgn,end);
// lane sub takes elements bgn+sub, +4, +8, ... Perfect quad balance and the
// quad's 4 loads are one contiguous 64B chunk. Disjointness across lanes
// preserved -> per-lane exact reservoirs.
#define SEGPROC(bgn, end) do { \
    int _j = (bgn) + sub, _je = (end); \
    for (; _j + 4 < _je; _j += 8) { \
        float4 _p0 = cs[_j]; float4 _p1 = cs[_j+4]; \
        PROC(_p0); PROC(_p1); \
    } \
    if (_j < _je) { float4 _p0 = cs[_j]; PROC(_p0); } \
} while (0)

// quad-min of the four lanes' current 10th keys; low word forced to all-ones
// so ties on the distance bits still pass the gate (tie-exact).
#define QEXCH() do { \
    unsigned long long _o1 = __shfl_xor(k9, 1, 4); \
    unsigned long long _m1 = (_o1 < k9) ? _o1 : k9; \
    unsigned long long _o2 = __shfl_xor(_m1, 2, 4); \
    unsigned long long _qm = (_o2 < _m1) ? _o2 : _m1; \
    qbK = _qm | 0xFFFFFFFFull; \
    kgate = (k9 < qbK) ? k9 : qbK; \
} while (0)

// R24 quad EXTRACTION merge: 10 rounds; per round a 2-stage u64-min butterfly
// finds the global min of the 4 sorted lists, every lane records it, every
// lane whose head equals it shifts down (shared keys collapse -> natural
// dedupe). Exact top-10 of the union, ascending, IDENTICAL in all 4 lanes.
#define QMERGE() do { \
    unsigned long long fin[KNN]; \
    _Pragma("unroll") \
    for (int r = 0; r < KNN; ++r) { \
        unsigned long long m = keys[0]; \
        unsigned long long _o1 = __shfl_xor(m, 1, 4); m = (_o1 < m) ? _o1 : m; \
        unsigned long long _o2 = __shfl_xor(m, 2, 4); m = (_o2 < m) ? _o2 : m; \
        fin[r] = m; \
        bool own = (keys[0] == m); \
        _Pragma("unroll") \
        for (int t = 0; t < KNN-1; ++t) keys[t] = own ? keys[t+1] : keys[t]; \
        keys[KNN-1] = own ? 0xFFFFFFFFFFFFFFFFull : keys[KNN-1]; \
    } \
    _Pragma("unroll") \
    for (int s = 0; s < KNN; ++s) keys[s] = fin[s]; \
    k9 = keys[KNN-1]; \
} while (0)

// ---------------------------------------------------------------------------
// Kernel D (R29 = R28 + NaN-gate on phase 3): grid 10-NN, FOUR lanes/query.
// Phases 1/2 unchanged. Phase 3 (rho=3 shell) now runs ONLY for unresolved
// quads that HOLD 10 KEYS (worst_m finite): for them the worst_m pruning
// works and resolution is cheap. Under-filled quads (worst_m = NaN — R28's
// regression: every box test NaN-passes -> they walked the whole 74-cell
// shell with an accept-everything gate) skip phase 3 and overflow to brute
// exactly as in R25. The gate only selects which verified-exact path each
// quad takes (R28 finite path / R25 NaN path) => bit-identical output.
// ---------------------------------------------------------------------------
__global__ __launch_bounds__(256) void knn_main_kernel(
    const float4* __restrict__ P4, const float4* __restrict__ S,
    const int2* __restrict__ combo, float4* __restrict__ Cov,
    int* __restrict__ ovf, unsigned long long* __restrict__ ovf_key,
    int* __restrict__ ovf_count)
{
    int b = blockIdx.x;                         // 0..1023
    int bb = ((b & 31) << 5) | (b >> 5);        // 5<->5 bit swap (bijective)
    int tidg = bb * 256 + threadIdx.x;          // 0..262143
    int qid  = tidg >> 2;                       // 0..65535
    int sub  = tidg & 3;
    int pair = qid >> 13;                       // 8 clouds
    int spos = qid & (NN - 1);                  // sorted position
    const float4* __restrict__ cl = P4 + (size_t)pair * NN;
    const float4* __restrict__ cs = S  + (size_t)pair * NN;
    const int2*   __restrict__ cb = combo + (size_t)pair * NCELLS;

    float4 q = cs[spos];
    float qx = q.x, qy = q.y, qz = q.z;
    int qi = __float_as_int(q.w);               // original index in cloud
    int qcx = cellc(qx), qcy = cellc(qy), qcz = cellc(qz);

    unsigned long long keys[KNN];
    #pragma unroll
    for (int s = 0; s < KNN; ++s) keys[s] = 0xFFFFFFFFFFFFFFFFull;
    unsigned long long k9    = 0xFFFFFFFFFFFFFFFFull;
    unsigned long long qbK   = 0xFFFFFFFFFFFFFFFFull;
    unsigned long long kgate = 0xFFFFFFFFFFFFFFFFull;

    // ---- phase 1: rho<=1 cube = 9 (z,y) rows, center-out order so gates
    // tighten early; QEXCH between rows shares the quad bound.
    int x0 = max(qcx - 1, 0), x1 = min(qcx + 1, G - 1);
    {
        const int DZ9[9] = { 0,  0,  0, -1,  1, -1, -1,  1,  1};
        const int DY9[9] = { 0,  1, -1,  0,  0, -1,  1, -1,  1};
        int rb[9], re[9];
        #pragma unroll
        for (int r = 0; r < 9; ++r) {
            int zz = qcz + DZ9[r], yy = qcy + DY9[r];
            rb[r] = 0; re[r] = 0;
            if ((unsigned)zz < G && (unsigned)yy < G) {
                int cbase = (zz*G + yy)*G;
                int2 a  = cb[cbase + x0];
                int2 b2 = cb[cbase + x1];
                rb[r] = a.x; re[r] = b2.x + b2.y;
            }
        }
        #pragma unroll
        for (int r = 0; r < 9; ++r) {
            SEGPROC(rb[r], re[r]);
            if (r == 0 || r == 2 || r == 4 || r == 6) QEXCH();
        }
    }

    // ---- quad extraction-merge -> exact cube top-10, identical in all lanes
    QMERGE();
    const unsigned long long k9M = k9;          // exact cube 10th (u64 key)
    float worstM = __uint_as_float((unsigned)(k9M >> 32)); // NaN if <10 found

    // ---- phase 2: rho=2 shell. Exterior of the cube is >= H from q, so
    // skip iff H^2 > worstM is EXACT (NaN-safe: NaN -> walk shell).
    bool skip = (H*H > worstM);                 // quad-uniform (worstM shared)

    qbK   = 0xFFFFFFFFFFFFFFFFull;              // phase-2 gate = own 10th
    kgate = k9;
    if (!skip) {
        int xs0 = max(qcx - 2, 0), xs1 = min(qcx + 2, G - 1);
        // 16 outer rows; box test redundant in all 4 lanes (same q -> same
        // result, quad-uniform branch), then cooperative stride-4 walk.
        const int SZ16[16] = {-2,-2,-2,-2,-2,  2, 2, 2, 2, 2, -1,-1, 0, 0, 1, 1};
        const int SY16[16] = {-2,-1, 0, 1, 2, -2,-1, 0, 1, 2, -2, 2,-2, 2,-2, 2};
        #pragma unroll
        for (int r = 0; r < 16; ++r) {
            int zz = qcz + SZ16[r], yy = qcy + SY16[r];
            if ((unsigned)zz < G && (unsigned)yy < G) {
                float loy = fmaf((float)yy, H, GRID_LO);
                float loz = fmaf((float)zz, H, GRID_LO);
                float py = fmaxf(0.0f, fmaxf(loy - qy, qy - (loy + H)));
                float pz = fmaxf(0.0f, fmaxf(loz - qz, qz - (loz + H)));
                float pyz = fmaf(pz, pz, py*py);
                if (!(pyz > worstM)) {
                    int cbase = (zz*G + yy)*G;
                    int2 a  = cb[cbase + xs0];
                    int2 b2 = cb[cbase + xs1];
                    SEGPROC(a.x, b2.x + b2.y);
                }
            }
        }
        // 18 isolated cells (|dz|<=1,|dy|<=1, dx=+/-2)
        const int CZ18[18] = {-1,-1,-1,-1,-1,-1,  0, 0, 0, 0, 0, 0,  1, 1, 1, 1, 1, 1};
        const int CY18[18] = {-1,-1, 0, 0, 1, 1, -1,-1, 0, 0, 1, 1, -1,-1, 0, 0, 1, 1};
        const int CX18[18] = {-2, 2,-2, 2,-2, 2, -2, 2,-2, 2,-2, 2, -2, 2,-2, 2,-2, 2};
        #pragma unroll
        for (int r = 0; r < 18; ++r) {
            int zz = qcz + CZ18[r], yy = qcy + CY18[r], xx = qcx + CX18[r];
            if ((unsigned)zz < G && (unsigned)yy < G && (unsigned)xx < G) {
                float lox = fmaf((float)xx, H, GRID_LO);
                float loy = fmaf((float)yy, H, GRID_LO);
                float loz = fmaf((float)zz, H, GRID_LO);
                float px = fmaxf(0.0f, fmaxf(lox - qx, qx - (lox + H)));
                float py = fmaxf(0.0f, fmaxf(loy - qy, qy - (loy + H)));
                float pz = fmaxf(0.0f, fmaxf(loz - qz, qz - (loz + H)));
                float m2 = fmaf(pz, pz, fmaf(py, py, px*px));
                if (!(m2 > worstM)) {
                    int2 a = cb[(zz*G + yy)*G + xx];
                    SEGPROC(a.x, a.x + a.y);
                }
            }
        }
    }

    // ---- phase-2 final merge (only if some lane inserted; quad-uniform)
    if (!skip) {
        int ch = (k9 != k9M) ? 1 : 0;
        ch |= __shfl_xor(ch, 1, 4);
        ch |= __shfl_xor(ch, 2, 4);
        if (ch) QMERGE();
    }
    float worst_m = __uint_as_float((unsigned)(k9 >> 32));

    // resolved at 2H iff cells beyond rho<=2 (gap >= 2H) cannot contribute
    float bf = (float)RCAP * H;
    bool resolved = (bf*bf > worst_m);          // strict; NaN (unfilled) -> false

    // ---- phase 3 (R29): rho=3 shell ONLY for unresolved quads with a FULL
    // list (worst_m finite -> pruning effective). NaN quads skip (they were
    // R28's walk-everything regression) and overflow with the R25 semantics.
    // Branch is quad-uniform (worst_m shared after merge) -> shfls safe.
    if (!resolved && (worst_m == worst_m)) {
        const unsigned long long k9P2 = k9;     // state after phase-2 merge
        qbK   = 0xFFFFFFFFFFFFFFFFull;
        kgate = k9;
        int xt0 = max(qcx - 3, 0), xt1 = min(qcx + 3, G - 1);
        // 24 outer rows (|dz|==3 or |dy|==3), contiguous x in [qcx-3,qcx+3]
        const int SZ24[24] = {-3,-3,-3,-3,-3,-3,-3,  3, 3, 3, 3, 3, 3, 3,
                              -2,-2,-1,-1, 0, 0, 1, 1, 2, 2};
        const int SY24[24] = {-3,-2,-1, 0, 1, 2, 3, -3,-2,-1, 0, 1, 2, 3,
                              -3, 3,-3, 3,-3, 3,-3, 3,-3, 3};
        #pragma unroll
        for (int r = 0; r < 24; ++r) {
            int zz = qcz + SZ24[r], yy = qcy + SY24[r];
            if ((unsigned)zz < G && (unsigned)yy < G) {
                float loy = fmaf((float)yy, H, GRID_LO);
                float loz = fmaf((float)zz, H, GRID_LO);
                float py = fmaxf(0.0f, fmaxf(loy - qy, qy - (loy + H)));
                float pz = fmaxf(0.0f, fmaxf(loz - qz, qz - (loz + H)));
                float pyz = fmaf(pz, pz, py*py);
                if (!(pyz > worst_m)) {
                    int cbase = (zz*G + yy)*G;
                    int2 a  = cb[cbase + xt0];
                    int2 b2 = cb[cbase + xt1];
                    SEGPROC(a.x, b2.x + b2.y);
                }
            }
        }
        // 50 isolated cells: |dz|<=2, |dy|<=2, dx = +/-3
        #pragma unroll 1
        for (int r = 0; r < 50; ++r) {
            int dz = (r / 10) - 2;
            int dy = ((r >> 1) % 5) - 2;
            int dx = (r & 1) ? 3 : -3;
            int zz = qcz + dz, yy = qcy + dy, xx = qcx + dx;
            if ((unsigned)zz < G && (unsigned)yy < G && (unsigned)xx < G) {
                float lox = fmaf((float)xx, H, GRID_LO);
                float loy = fmaf((float)yy, H, GRID_LO);
                float loz = fmaf((float)zz, H, GRID_LO);
                float px = fmaxf(0.0f, fmaxf(lox - qx, qx - (lox + H)));
                float py = fmaxf(0.0f, fmaxf(loy - qy, qy - (loy + H)));
                float pz = fmaxf(0.0f, fmaxf(loz - qz, qz - (loz + H)));
                float m2 = fmaf(pz, pz, fmaf(py, py, px*px));
                if (!(m2 > worst_m)) {
                    int2 a = cb[(zz*G + yy)*G + xx];
                    SEGPROC(a.x, a.x + a.y);
                }
            }
        }
        int ch = (k9 != k9P2) ? 1 : 0;
        ch |= __shfl_xor(ch, 1, 4);
        ch |= __shfl_xor(ch, 2, 4);
        if (ch) QMERGE();
        worst_m = __uint_as_float((unsigned)(k9 >> 32));
        float bf3 = 3.0f * H;
        resolved = (bf3*bf3 > worst_m);         // cells beyond rho<=3: gap>=3H
    }

    if (resolved && sub == 0) {
        float c[6];
        cov_compute(cl, keys, c);               // sub==0 only: 1/4 gather loads
        size_t o = ((size_t)pair*NN + qi)*2;
        Cov[o]   = make_float4(c[0], c[1], c[2], c[3]);
        Cov[o+1] = make_float4(c[4], c[5], 0.0f, 0.0f);
    } else if (!resolved && sub == 0) {
        int pos = atomicAdd(ovf_count, 1);
        ovf[pos] = (pair << 13) | qi;
        ovf_key[pos] = k9;      // exact 10th over examined set: valid upper
    }                           // bound on the true 10th key (NaN if <10)
}

// ---------------------------------------------------------------------------
// Kernel D2 (R29 = R28 config): brute-force overflow, ONE BLOCK (256 thr =
// 4 waves) per query, 2048 blocks. Overflow is now mostly the NaN (sparse-
// tail) queries (~hundreds) plus rare rho>3 cases with tight bounds — one
// residency round, small total. Merge path: per-wave 10-round extraction,
// lane 0 posts to LDS, thread 0 4-list head-pointer merge. Exact top-10 of
// the union ascending => bit-identical.
// ---------------------------------------------------------------------------
#define BRUTE_BLOCKS 2048
__global__ __launch_bounds__(256) void brute_kernel(
    const float4* __restrict__ P4, const int* __restrict__ ovf,
    const unsigned long long* __restrict__ ovf_key,
    const int* __restrict__ ovf_count, float4* __restrict__ Cov)
{
    __shared__ unsigned long long wl[4][KNN];
    int tid = threadIdx.x;
    int lane = tid & 63;
    int wid = tid >> 6;
    int count = *ovf_count;

    for (int oi = blockIdx.x; oi < count; oi += BRUTE_BLOCKS) {
        int rec = ovf[oi];
        unsigned long long bound = ovf_key[oi];
        float bound_d = __uint_as_float((unsigned)(bound >> 32)); // NaN if unfilled
        int pair = rec >> 13;
        int qi = rec & (NN - 1);
        const float4* __restrict__ cl = P4 + (size_t)pair * NN;
        float4 q = cl[qi];
        float qx = q.x, qy = q.y, qz = q.z;

        unsigned long long keys[KNN];
        #pragma unroll
        for (int s = 0; s < KNN; ++s) keys[s] = 0xFFFFFFFFFFFFFFFFull;
        unsigned long long k9 = keys[KNN-1];

        // per-thread scan of a disjoint 1/256 slice (32 candidates), bound-
        // gated; ties at dd==bound_d pass (exact). Coalesced cl[i*256+tid].
#define BPROC(p, jj) do { \
        float ddx = qx - (p).x, ddy = qy - (p).y, ddz = qz - (p).z; \
        float dd = fmaf(ddz, ddz, fmaf(ddy, ddy, ddx*ddx)); \
        if (!(dd > bound_d)) { \
            unsigned long long key = \
                ((unsigned long long)__float_as_uint(dd) << 32) | (unsigned)(jj); \
            if (key < k9) { \
                unsigned long long ck = key; \
                _Pragma("unroll") \
                for (int s = 0; s < KNN; ++s) { \
                    unsigned long long ok2 = keys[s]; \
                    bool sw = ok2 > ck; \
                    keys[s] = sw ? ck : ok2; \
                    ck      = sw ? ok2 : ck; \
                } \
                k9 = keys[KNN-1]; \
            } \
        } \
    } while (0)
        #pragma unroll 1
        for (int i = 0; i < 32; i += 4) {       // 8 iters, 4 loads in flight
            float4 p0 = cl[(i+0)*256 + tid];
            float4 p1 = cl[(i+1)*256 + tid];
            float4 p2 = cl[(i+2)*256 + tid];
            float4 p3 = cl[(i+3)*256 + tid];
            BPROC(p0, (i+0)*256 + tid);
            BPROC(p1, (i+1)*256 + tid);
            BPROC(p2, (i+2)*256 + tid);
            BPROC(p3, (i+3)*256 + tid);
        }
#undef BPROC

        // per-wave 10-round extraction merge: exact wave top-10, ascending,
        // identical in all 64 lanes (sentinel ties shift all owners — safe).
        unsigned long long fin[KNN];
        #pragma unroll
        for (int r = 0; r < KNN; ++r) {
            unsigned long long m = keys[0];
            #pragma unroll
            for (int off = 1; off < 64; off <<= 1) {
                unsigned long long o = __shfl_xor(m, off);
                m = (o < m) ? o : m;
            }
            fin[r] = m;
            if (keys[0] == m) {
                #pragma unroll
                for (int t = 0; t < KNN-1; ++t) keys[t] = keys[t+1];
                keys[KNN-1] = 0xFFFFFFFFFFFFFFFFull;
            }
        }

        if (lane == 0) {
            #pragma unroll
            for (int s = 0; s < KNN; ++s) wl[wid][s] = fin[s];
        }
        __syncthreads();
        if (tid == 0) {
            // 4-list head-pointer extraction merge (lists sorted ascending).
            // Real keys unique -> exactly one list advances; equal sentinels
            // advance together (reads precede advances; idx <= round <= 9).
            int i0 = 0, i1 = 0, i2 = 0, i3 = 0;
            unsigned long long outk[KNN];
            #pragma unroll
            for (int r = 0; r < KNN; ++r) {
                unsigned long long h0 = wl[0][i0], h1 = wl[1][i1];
                unsigned long long h2 = wl[2][i2], h3 = wl[3][i3];
                unsigned long long m01 = (h0 < h1) ? h0 : h1;
                unsigned long long m23 = (h2 < h3) ? h2 : h3;
                unsigned long long m   = (m01 < m23) ? m01 : m23;
                outk[r] = m;
                i0 += (h0 == m); i1 += (h1 == m);
                i2 += (h2 == m); i3 += (h3 == m);
            }
            float c[6];
            cov_compute(cl, outk, c);
            size_t o = ((size_t)pair*NN + qi)*2;
            Cov[o]   = make_float4(c[0], c[1], c[2], c[3]);
            Cov[o+1] = make_float4(c[4], c[5], 0.0f, 0.0f);
        }
        __syncthreads();                        // protect wl for next query
    }
}

// ---------------------------------------------------------------------------
// Kernel E (R19): fused eigh + loss, ONE eigh per thread over 2*BN threads.
// Thread 2k handles gt[k], thread 2k+1 handles pred[k]; normals exchanged
// in-wave via shfl_xor(1); even lanes compute 1-cos; block reduce; atomic.
// Identical eigh inputs -> bit-identical normals (summation grouping only).
// ---------------------------------------------------------------------------
__global__ __launch_bounds__(256) void eigh_loss_kernel(
    const float4* __restrict__ Cov, float* __restrict__ accum,
    unsigned* __restrict__ counter, float* __restrict__ out)
{
    int tid = threadIdx.x;
    int t = blockIdx.x * 256 + tid;            // 0..2*BN-1
    int k = t >> 1;                            // pair index 0..BN-1
    int cld = t & 1;                           // 0 = gt, 1 = pred
    size_t ci = ((size_t)(cld ? BN + k : k)) * 2;
    float4 a0 = Cov[ci], a1 = Cov[ci + 1];
    float n[3];
    eigh3_smallest(a0.x, a0.y, a0.z, a0.w, a1.x, a1.y, n);

    // exchange with partner lane (2k <-> 2k+1 always share a wave)
    float ox = __shfl_xor(n[0], 1);
    float oy = __shfl_xor(n[1], 1);
    float oz = __shfl_xor(n[2], 1);

    float v = 0.0f;
    if (cld == 0) {
        float gx=n[0], gy=n[1], gz=n[2];
        float hx=ox,  hy=oy,  hz=oz;
        float dot = fmaf(gx,hx,fmaf(gy,hy,gz*hz));
        float ng  = sqrtf(fmaf(gx,gx,fmaf(gy,gy,gz*gz)));
        float nh  = sqrtf(fmaf(hx,hx,fmaf(hy,hy,hz*hz)));
        float den = fmaxf(ng*nh, 1e-8f);
        v = 1.0f - dot/den;
    }

    __shared__ float red[256];
    red[tid] = v;                              // odd lanes contribute 0
    __syncthreads();
    for (int s = 128; s > 0; s >>= 1) {
        if (tid < s) red[tid] += red[tid+s];
        __syncthreads();
    }
    if (tid == 0) {
        atomicAdd(accum, red[0]);
        __threadfence();
        unsigned old = atomicAdd(counter, 1u);
        if (old == (unsigned)(2*BN/256 - 1)) {
            float tot = atomicAdd(accum, 0.0f);
            out[0] = tot * (1.0f/(float)BN);
        }
    }
}

// ---------------------------------------------------------------------------
extern "C" void kernel_launch(void* const* d_in, const int* in_sizes, int n_in,
                              void* d_out, int out_size, void* d_ws, size_t ws_size,
                              hipStream_t stream)
{
    (void)in_sizes; (void)n_in; (void)out_size; (void)ws_size;
    const float*    gt   = (const float*)d_in[0];
    const float*    pred = (const float*)d_in[1];
    const unsigned* idxw = (const unsigned*)d_in[2];
    float* out = (float*)d_out;

    char* w = (char*)d_ws;
    float4* P4   = (float4*)w;                         w += (size_t)2*BN*16;   // 1 MB
    float4* S    = (float4*)w;                         w += (size_t)2*BN*16;   // 1 MB
    int*    hist = (int*)w;                            w += (size_t)8*NCELLS*4;   // 1 MB
    int2*   combo = (int2*)w;                          w += (size_t)8*NCELLS*8;   // 2 MB
    float4* Cov  = (float4*)w;                         w += (size_t)2*BN*32;   // 2 MB
    float*  accum = (float*)w;                         w += 16;
    unsigned* counter = (unsigned*)(accum + 1);
    int*    ovf_count = (int*)(accum + 2);
    int*    ovf  = (int*)w;                            w += (size_t)2*BN*4;    // 0.25 MB
    unsigned long long* ovf_key = (unsigned long long*)w;  w += (size_t)2*BN*8; // 0.5 MB

    hipMemsetAsync(hist, 0, (size_t)8*NCELLS*4, stream);
    hipLaunchKernelGGL(prep_kernel,    dim3(2*BN/256), dim3(256),  0, stream,
                       gt, pred, idxw, P4, hist, accum, counter, ovf_count);
    hipLaunchKernelGGL(scan_kernel,    dim3(8),        dim3(1024), 0, stream,
                       hist, combo);
    hipLaunchKernelGGL(scatter_kernel, dim3(2*BN/256), dim3(256),  0, stream,
                       P4, hist, combo, S);
    hipLaunchKernelGGL(knn_main_kernel, dim3(2*BN*4/256), dim3(256), 0, stream,
                       P4, S, combo, Cov, ovf, ovf_key, ovf_count);
    hipLaunchKernelGGL(brute_kernel,   dim3(BRUTE_BLOCKS), dim3(256), 0, stream,
                       P4, ovf, ovf_key, ovf_count, Cov);
    hipLaunchKernelGGL(eigh_loss_kernel, dim3(2*BN/256), dim3(256), 0, stream,
                       Cov, accum, counter, out);
}